// Round 5
// baseline (403.358 us; speedup 1.0000x reference)
//
#include <hip/hip_runtime.h>
#include <math.h>

#define SEQL   45000
#define NBAT   2
#define CCH    32
#define NSEL   512
#define NHEAD  4
#define DKD    32
#define HDD    128
#define MLPD   512
#define TKCAP  2048
#define TKB    32     // scan blocks per (b,channel)

// bf16 helpers: round-to-nearest-even pack, cheap unpack (<<16)
__device__ inline unsigned short f2bf(float x) {
  unsigned u = __float_as_uint(x);
  u = (u + 0x7fffu + ((u >> 16) & 1u)) >> 16;
  return (unsigned short)u;
}
#define BFL(u) __uint_as_float((u) << 16)
#define BFH(u) __uint_as_float((u) & 0xffff0000u)

// ---------------- K0: basis feature table E[a][16] in bf16 ------------------
__global__ void build_etab_kernel(unsigned short* __restrict__ E) {
  int a = blockIdx.x * blockDim.x + threadIdx.x;
  if (a >= SEQL) return;
  float ad = (float)a;
  float out[16];
  float log2S = log2f((float)SEQL);
  #pragma unroll
  for (int k = 0; k < 5; ++k) {
    float hl = exp2f(3.0f + (float)k * (log2S - 3.0f) * 0.25f);
    out[k] = exp2f(-ad / hl);
  }
  const int cw[5] = {1, 3, 7, 15, 31};
  #pragma unroll
  for (int k = 0; k < 5; ++k) out[5 + k] = (a < cw[k]) ? 1.0f : 0.0f;
  float pmax = 0.0f;
  float pk[5];
  #pragma unroll
  for (int k = 0; k < 5; ++k) {
    float mean = 9000.0f * (float)(k + 1);
    float sd = 4500.0f;
    float cc = (mean / sd) * (mean / sd);      // 4,16,36,64,100
    float rr = mean / (sd * sd);
    float logz = lgammaf(cc) - cc * logf(rr);
    float p;
    if (a == 0) p = 1e-8f;                     // xlogy -> -inf -> exp = 0
    else p = expf((cc - 1.0f) * logf(ad) - rr * ad - logz) + 1e-8f;
    pk[k] = p;
    float mstar = (cc - 1.0f) / rr;            // 6750 .. 44550, in range
    float m0 = floorf(mstar), m1 = m0 + 1.0f;
    if (m1 > (float)(SEQL - 1)) m1 = (float)(SEQL - 1);
    float p0 = expf((cc - 1.0f) * logf(m0) - rr * m0 - logz) + 1e-8f;
    float p1 = expf((cc - 1.0f) * logf(m1) - rr * m1 - logz) + 1e-8f;
    pmax = fmaxf(pmax, fmaxf(p0, p1));
  }
  #pragma unroll
  for (int k = 0; k < 5; ++k) out[10 + k] = pk[k] / pmax;
  out[15] = 0.0f;
  uint4 o0, o1;
  o0.x = (unsigned)f2bf(out[0])  | ((unsigned)f2bf(out[1])  << 16);
  o0.y = (unsigned)f2bf(out[2])  | ((unsigned)f2bf(out[3])  << 16);
  o0.z = (unsigned)f2bf(out[4])  | ((unsigned)f2bf(out[5])  << 16);
  o0.w = (unsigned)f2bf(out[6])  | ((unsigned)f2bf(out[7])  << 16);
  o1.x = (unsigned)f2bf(out[8])  | ((unsigned)f2bf(out[9])  << 16);
  o1.y = (unsigned)f2bf(out[10]) | ((unsigned)f2bf(out[11]) << 16);
  o1.z = (unsigned)f2bf(out[12]) | ((unsigned)f2bf(out[13]) << 16);
  o1.w = (unsigned)f2bf(out[14]);
  uint4* E4 = (uint4*)(E + (size_t)a * 16);
  E4[0] = o0;
  E4[1] = o1;
}

// ---------------- K1a: distributed 16-bit-key histogram ---------------------
__global__ __launch_bounds__(256) void topk_hist_kernel(const float* __restrict__ att,
                                                        int* __restrict__ hist) {
  int ch4 = blockIdx.x / TKB;
  int blk = blockIdx.x % TKB;
  int b = ch4 >> 1, ch = ch4 & 1;
  const float* row = att + ((size_t)b * 3 + 1 + ch) * SEQL;
  int* h = hist + (size_t)ch4 * 65536;
  int per = (SEQL + TKB - 1) / TKB;
  int lo = blk * per;
  int hi = lo + per; if (hi > SEQL) hi = SEQL;
  for (int i = lo + threadIdx.x; i < hi; i += 256)
    atomicAdd(&h[__float_as_uint(row[i]) >> 16], 1);   // vals >= 0 -> monotone
}

// ---------------- K1b: find 16-bit threshold via parallel suffix scan -------
__global__ __launch_bounds__(1024) void topk_thresh_kernel(const int* __restrict__ hist,
                                                           int* __restrict__ thr) {
  const int* h = hist + (size_t)blockIdx.x * 65536;
  __shared__ int s[1024];
  __shared__ int sh_t;
  int t = threadIdx.x;
  int base = t * 64;
  int loc[64];
  int sum = 0;
  #pragma unroll
  for (int i = 0; i < 16; ++i) {
    int4 v = ((const int4*)(h + base))[i];
    loc[i * 4 + 0] = v.x; loc[i * 4 + 1] = v.y;
    loc[i * 4 + 2] = v.z; loc[i * 4 + 3] = v.w;
    sum += v.x + v.y + v.z + v.w;
  }
  s[t] = sum;
  __syncthreads();
  for (int d = 1; d < 1024; d <<= 1) {
    int v = s[t] + ((t + d < 1024) ? s[t + d] : 0);
    __syncthreads();
    s[t] = v;
    __syncthreads();
  }
  int sufEx = (t == 1023) ? 0 : s[t + 1];
  if (s[t] >= 256 && sufEx < 256) sh_t = t;    // unique crossing chunk
  __syncthreads();
  if (t == sh_t) {
    int acc = sufEx;
    int T16 = base;
    for (int i = 63; i >= 0; --i) {
      acc += loc[i];
      if (acc >= 256) { T16 = base + i; break; }
    }
    thr[blockIdx.x] = T16;
  }
}

// ---------------- K1c: distributed candidate collect ------------------------
__global__ __launch_bounds__(256) void topk_collect_kernel(const float* __restrict__ att,
                                                           const int* __restrict__ thr,
                                                           unsigned long long* __restrict__ cand,
                                                           int* __restrict__ cnt) {
  int ch4 = blockIdx.x / TKB;
  int blk = blockIdx.x % TKB;
  int b = ch4 >> 1, ch = ch4 & 1;
  const float* row = att + ((size_t)b * 3 + 1 + ch) * SEQL;
  unsigned T16 = (unsigned)thr[ch4];
  int per = (SEQL + TKB - 1) / TKB;
  int lo = blk * per;
  int hi = lo + per; if (hi > SEQL) hi = SEQL;
  for (int i = lo + threadIdx.x; i < hi; i += 256) {
    unsigned key = __float_as_uint(row[i]);
    if ((key >> 16) >= T16) {
      int p = atomicAdd(&cnt[ch4], 1);
      if (p < TKCAP)
        cand[(size_t)ch4 * TKCAP + p] =
            ((unsigned long long)key << 32) | (unsigned)(~(unsigned)i);
    }
  }
}

// ---------------- K1d: sort candidates desc (both channels) + merge ---------
// 2 blocks (per batch): two sequential 2048-desc-sorts -> top-256 each,
// then one ascending 512 bitonic of the merged indices.
__global__ __launch_bounds__(1024) void topk_sortmerge_kernel(
    const unsigned long long* __restrict__ cand, const int* __restrict__ cnt,
    int* __restrict__ idx) {
  __shared__ unsigned long long sc[TKCAP];
  __shared__ int m[512];
  int b = blockIdx.x, t = threadIdx.x;
  for (int ch = 0; ch < 2; ++ch) {
    int ch4 = b * 2 + ch;
    int n = cnt[ch4]; if (n > TKCAP) n = TKCAP;
    for (int i = t; i < TKCAP; i += 1024)
      sc[i] = (i < n) ? cand[(size_t)ch4 * TKCAP + i] : 0ull;
    __syncthreads();
    for (int k = 2; k <= TKCAP; k <<= 1) {
      for (int j = k >> 1; j > 0; j >>= 1) {
        for (int i = t; i < TKCAP; i += 1024) {
          int ixj = i ^ j;
          if (ixj > i) {
            unsigned long long va = sc[i], vb2 = sc[ixj];
            bool up = ((i & k) == 0);
            if ((va < vb2) == up) { sc[i] = vb2; sc[ixj] = va; }
          }
        }
        __syncthreads();
      }
    }
    if (t < 256)
      m[ch * 256 + t] = (int)~(unsigned)(sc[t] & 0xFFFFFFFFull);
    __syncthreads();
  }
  for (int k = 2; k <= 512; k <<= 1) {
    for (int j = k >> 1; j > 0; j >>= 1) {
      if (t < 512) {
        int ixj = t ^ j;
        if (ixj > t) {
          int va = m[t], vb2 = m[ixj];
          bool up = ((t & k) == 0);
          if ((va > vb2) == up) { m[t] = vb2; m[ixj] = va; }
        }
      }
      __syncthreads();
    }
  }
  if (t < 512) idx[b * 512 + t] = m[t];
}

// ---------------- K2: gather emb rows ---------------------------------------
__global__ void gather_kernel(const float* __restrict__ x, const int* __restrict__ idx,
                              float* __restrict__ emb) {
  int t = blockIdx.x * 256 + threadIdx.x;
  if (t >= NBAT * NSEL * CCH) return;
  int c = t & 31;
  int i = (t >> 5) & 511;
  int b = t >> 14;
  emb[t] = x[((size_t)b * CCH + c) * SEQL + idx[b * NSEL + i]];
}

// ---------------- K3: LN1 + QKV + rel-weight factorization ------------------
// kbT/vT layout (bf16): [((b*4+h)*4+dpack)*4096 + i*8 + (d&7)]
__global__ __launch_bounds__(128) void qkv_kernel(
    const float* __restrict__ emb,
    const float* __restrict__ ln_g, const float* __restrict__ ln_b,
    const float* __restrict__ Wq, const float* __restrict__ Wk,
    const float* __restrict__ Wv, const float* __restrict__ Wrel,
    const float* __restrict__ rcb, const float* __restrict__ rpb,
    float* __restrict__ qc, unsigned short* __restrict__ kbT,
    unsigned short* __restrict__ vT, float* __restrict__ wb, int layer) {
  __shared__ float qs[4][128];
  int hd = threadIdx.x;        // 0..127
  int hh = hd >> 5, d = hd & 31;
  const float* g = ln_g + layer * CCH;
  const float* bb = ln_b + layer * CCH;
  const float* wq = Wq + (size_t)layer * CCH * HDD + hd;
  const float* wk = Wk + (size_t)layer * CCH * HDD + hd;
  const float* wv = Wv + (size_t)layer * CCH * HDD + hd;
  #pragma unroll
  for (int r = 0; r < 4; ++r) {
    int row = blockIdx.x * 4 + r;          // b*512 + i
    int b = row >> 9, ii = row & 511;
    const float* e = emb + (size_t)row * CCH;
    float h[32];
    float mu = 0.f;
    #pragma unroll
    for (int c = 0; c < 32; ++c) { h[c] = e[c]; mu += h[c]; }
    mu *= (1.0f / 32.0f);
    float var = 0.f;
    #pragma unroll
    for (int c = 0; c < 32; ++c) { float dd0 = h[c] - mu; var += dd0 * dd0; }
    var *= (1.0f / 32.0f);
    float rstd = rsqrtf(var + 1e-5f);
    #pragma unroll
    for (int c = 0; c < 32; ++c) h[c] = (h[c] - mu) * rstd * g[c] + bb[c];
    float q = 0.f, kk = 0.f, vv = 0.f;
    #pragma unroll
    for (int c = 0; c < 32; ++c) {
      q += h[c] * wq[c * HDD];
      kk += h[c] * wk[c * HDD];
      vv += h[c] * wv[c * HDD];
    }
    q *= 0.17677669529663687f;   // DK^-0.5
    qs[r][hd] = q;
    qc[(size_t)row * HDD + hd] = q + rcb[(layer * NHEAD + hh) * DKD + d];
    size_t tpos = ((size_t)(b * 4 + hh) * 4 + (d >> 3)) * 4096 + (size_t)ii * 8 + (d & 7);
    kbT[tpos] = f2bf(kk);
    vT[tpos]  = f2bf(vv);
    __syncthreads();
    if (hd < 120) {
      int h2 = hd / 30, f = hd % 30;
      const float* wr = Wrel + ((size_t)layer * 30 + f) * HDD + h2 * DKD;
      const float* rp = rpb + (layer * NHEAD + h2) * DKD;
      const float* qsh = qs[r] + h2 * DKD;
      float acc = 0.f;
      #pragma unroll
      for (int dd = 0; dd < 32; ++dd) acc += (qsh[dd] + rp[dd]) * wr[dd];
      wb[((size_t)row * NHEAD + h2) * 32 + f] = acc;   // padded stride 32
    }
  }
}

// ---------------- K4: attention (content + rel + softmax + PV) --------------
// 1024 blocks (b, h, 4 i-rows), 4 waves, 1 row/wave. All-coalesced:
// k AND v via transposed bf16 layout; softmax p stays in REGISTERS
// (lane<->j mapping identical in QK and PV phases); per-wave VMEM ~80 instrs
// (was ~300 with the strided v walk + LDS p round-trip).
__global__ __launch_bounds__(256, 4) void attn_kernel(
    const float* __restrict__ qc, const unsigned short* __restrict__ kbT,
    const unsigned short* __restrict__ vT, const float* __restrict__ wbuf,
    const unsigned short* __restrict__ E, const int* __restrict__ idx,
    float* __restrict__ ob) {
  __shared__ int idxl[512];
  int bid = blockIdx.x;
  int b = bid >> 9;
  int h = (bid >> 7) & 3;
  int i0 = (bid & 127) * 4;
  int tid = threadIdx.x;
  int wv = tid >> 6, ln = tid & 63;
  for (int i = tid; i < 512; i += 256) idxl[i] = idx[b * NSEL + i];
  __syncthreads();
  int i = i0 + wv;
  const float* qrow = qc + (size_t)(b * NSEL + i) * HDD + h * DKD;
  float q[32];
  #pragma unroll
  for (int d4 = 0; d4 < 8; ++d4) {
    float4 qv = *(const float4*)(qrow + d4 * 4);
    q[d4 * 4 + 0] = qv.x; q[d4 * 4 + 1] = qv.y;
    q[d4 * 4 + 2] = qv.z; q[d4 * 4 + 3] = qv.w;
  }
  const float* wrow = wbuf + ((size_t)(b * NSEL + i) * NHEAD + h) * 32;
  float w0[15], w1[15];
  #pragma unroll
  for (int f = 0; f < 15; ++f) { w0[f] = wrow[f]; w1[f] = wrow[15 + f]; }
  int ii = idxl[i];
  const uint4* kb4 = (const uint4*)kbT + (size_t)(b * 4 + h) * 4 * 512;
  const uint4* vb4 = (const uint4*)vT + (size_t)(b * 4 + h) * 4 * 512;
  float lg[8];
  #pragma unroll
  for (int u = 0; u < 8; ++u) {
    int j = u * 64 + ln;
    int dj = ii - idxl[j];
    float cacc = 0.f;
    #pragma unroll
    for (int dp = 0; dp < 4; ++dp) {
      uint4 kv = kb4[dp * 512 + j];
      cacc += q[dp * 8 + 0] * BFL(kv.x) + q[dp * 8 + 1] * BFH(kv.x)
            + q[dp * 8 + 2] * BFL(kv.y) + q[dp * 8 + 3] * BFH(kv.y)
            + q[dp * 8 + 4] * BFL(kv.z) + q[dp * 8 + 5] * BFH(kv.z)
            + q[dp * 8 + 6] * BFL(kv.w) + q[dp * 8 + 7] * BFH(kv.w);
    }
    int a = dj < 0 ? -dj : dj;
    const uint4* er = (const uint4*)(E + (size_t)a * 16);
    uint4 e0 = er[0], e1 = er[1];
    float r0 = BFL(e0.x) * w0[0]  + BFH(e0.x) * w0[1]
             + BFL(e0.y) * w0[2]  + BFH(e0.y) * w0[3]
             + BFL(e0.z) * w0[4]  + BFH(e0.z) * w0[5]
             + BFL(e0.w) * w0[6]  + BFH(e0.w) * w0[7]
             + BFL(e1.x) * w0[8]  + BFH(e1.x) * w0[9]
             + BFL(e1.y) * w0[10] + BFH(e1.y) * w0[11]
             + BFL(e1.z) * w0[12] + BFH(e1.z) * w0[13]
             + BFL(e1.w) * w0[14];
    float r1 = BFL(e0.x) * w1[0]  + BFH(e0.x) * w1[1]
             + BFL(e0.y) * w1[2]  + BFH(e0.y) * w1[3]
             + BFL(e0.z) * w1[4]  + BFH(e0.z) * w1[5]
             + BFL(e0.w) * w1[6]  + BFH(e0.w) * w1[7]
             + BFL(e1.x) * w1[8]  + BFH(e1.x) * w1[9]
             + BFL(e1.y) * w1[10] + BFH(e1.y) * w1[11]
             + BFL(e1.z) * w1[12] + BFH(e1.z) * w1[13]
             + BFL(e1.w) * w1[14];
    float sgn = dj > 0 ? 1.f : (dj < 0 ? -1.f : 0.f);
    lg[u] = cacc + r0 + sgn * r1;
  }
  // full-row softmax across the wave (512 logits, 8/lane), all in registers
  float m = lg[0];
  #pragma unroll
  for (int u = 1; u < 8; ++u) m = fmaxf(m, lg[u]);
  #pragma unroll
  for (int s = 1; s < 64; s <<= 1) m = fmaxf(m, __shfl_xor(m, s));
  float ssum = 0.f;
  #pragma unroll
  for (int u = 0; u < 8; ++u) { lg[u] = expf(lg[u] - m); ssum += lg[u]; }
  #pragma unroll
  for (int s = 1; s < 64; s <<= 1) ssum += __shfl_xor(ssum, s);
  float invs = 1.0f / ssum;
  // PV: p in registers, v coalesced; butterfly-reduce 8 partial d-sums
  float* obrow = ob + (size_t)(b * NSEL + i) * HDD + h * DKD;
  #pragma unroll
  for (int dp = 0; dp < 4; ++dp) {
    float acc[8] = {0.f, 0.f, 0.f, 0.f, 0.f, 0.f, 0.f, 0.f};
    #pragma unroll
    for (int u = 0; u < 8; ++u) {
      uint4 vv = vb4[dp * 512 + u * 64 + ln];
      float p = lg[u];
      acc[0] += p * BFL(vv.x); acc[1] += p * BFH(vv.x);
      acc[2] += p * BFL(vv.y); acc[3] += p * BFH(vv.y);
      acc[4] += p * BFL(vv.z); acc[5] += p * BFH(vv.z);
      acc[6] += p * BFL(vv.w); acc[7] += p * BFH(vv.w);
    }
    #pragma unroll
    for (int s = 1; s < 64; s <<= 1) {
      #pragma unroll
      for (int t = 0; t < 8; ++t) acc[t] += __shfl_xor(acc[t], s);
    }
    // lane ln<8 writes d = dp*8+ln; select acc[ln] via cndmask chain
    int sel = ln & 7;
    float oval = acc[0];
    #pragma unroll
    for (int t = 1; t < 8; ++t) oval = (sel == t) ? acc[t] : oval;
    if (ln < 8) obrow[dp * 8 + ln] = oval * invs;
  }
}

// ---------------- K5: fused proj+residual+LN2+MLP+residual, 4 rows/block ----
__global__ __launch_bounds__(256) void mlp_kernel(
    const float* __restrict__ ob, const float* __restrict__ Wo,
    const float* __restrict__ bo,
    const float* __restrict__ ln_g, const float* __restrict__ ln_b,
    const float* __restrict__ W1, const float* __restrict__ b1,
    const float* __restrict__ W2, const float* __restrict__ b2,
    float* __restrict__ emb, int layer) {
  __shared__ float part[4][8][32];
  __shared__ float res[4][32];
  __shared__ float hln[4][32];
  __shared__ float a1s[4][MLPD];
  int row0 = blockIdx.x * 4;
  int tid = threadIdx.x;
  int c = tid & 31, seg = tid >> 5;
  const float* wo = Wo + (size_t)layer * HDD * CCH + c;
  float pacc[4] = {0.f, 0.f, 0.f, 0.f};
  #pragma unroll
  for (int k = 0; k < 16; ++k) {
    int kk = seg * 16 + k;
    float w = wo[kk * CCH];
    #pragma unroll
    for (int r = 0; r < 4; ++r)
      pacc[r] += ob[(size_t)(row0 + r) * HDD + kk] * w;
  }
  #pragma unroll
  for (int r = 0; r < 4; ++r) part[r][seg][c] = pacc[r];
  __syncthreads();
  if (tid < 128) {
    int r = tid >> 5, cc = tid & 31;
    float s = bo[layer * CCH + cc] + emb[(size_t)(row0 + r) * CCH + cc];
    #pragma unroll
    for (int sg = 0; sg < 8; ++sg) s += part[r][sg][cc];
    res[r][cc] = s;
  }
  __syncthreads();
  if (tid < 128) {
    int r = tid >> 5, cc = tid & 31;
    float mu = 0.f, s2 = 0.f;
    #pragma unroll
    for (int c2 = 0; c2 < 32; ++c2) { float v = res[r][c2]; mu += v; s2 += v * v; }
    mu *= (1.0f / 32.0f);
    float var = s2 * (1.0f / 32.0f) - mu * mu;
    float rstd = rsqrtf(var + 1e-5f);
    hln[r][cc] = (res[r][cc] - mu) * rstd * ln_g[layer * CCH + cc] + ln_b[layer * CCH + cc];
  }
  __syncthreads();
  const float* w1 = W1 + (size_t)layer * CCH * MLPD;
  float accA[4], accB[4];
  float bA = b1[layer * MLPD + tid], bB = b1[layer * MLPD + tid + 256];
  #pragma unroll
  for (int r = 0; r < 4; ++r) { accA[r] = bA; accB[r] = bB; }
  for (int c2 = 0; c2 < 32; ++c2) {
    float wa = w1[c2 * MLPD + tid];
    float wb2 = w1[c2 * MLPD + tid + 256];
    #pragma unroll
    for (int r = 0; r < 4; ++r) {
      float hv = hln[r][c2];
      accA[r] += hv * wa;
      accB[r] += hv * wb2;
    }
  }
  #pragma unroll
  for (int r = 0; r < 4; ++r) {
    a1s[r][tid]       = 0.5f * accA[r] * (1.0f + erff(accA[r] * 0.70710678118654752f));
    a1s[r][tid + 256] = 0.5f * accB[r] * (1.0f + erff(accB[r] * 0.70710678118654752f));
  }
  __syncthreads();
  const float* w2 = W2 + (size_t)layer * MLPD * CCH;
  float acc2[4] = {0.f, 0.f, 0.f, 0.f};
  #pragma unroll 4
  for (int mi = 0; mi < 64; ++mi) {
    int m = seg * 64 + mi;
    float w = w2[m * CCH + c];
    #pragma unroll
    for (int r = 0; r < 4; ++r) acc2[r] += a1s[r][m] * w;
  }
  __syncthreads();                    // part[] reuse
  #pragma unroll
  for (int r = 0; r < 4; ++r) part[r][seg][c] = acc2[r];
  __syncthreads();
  if (tid < 128) {
    int r = tid >> 5, cc = tid & 31;
    float s = b2[layer * CCH + cc] + res[r][cc];
    #pragma unroll
    for (int sg = 0; sg < 8; ++sg) s += part[r][sg][cc];
    emb[(size_t)(row0 + r) * CCH + cc] = s;
  }
}

// ---------------- K7: scatter back ------------------------------------------
__global__ void scatter_kernel(const float* __restrict__ emb, const int* __restrict__ idx,
                               float* __restrict__ out) {
  int t = blockIdx.x * 256 + threadIdx.x;
  if (t >= NBAT * NSEL * CCH) return;
  int c = t & 31;
  int i = (t >> 5) & 511;
  int b = t >> 14;
  out[((size_t)b * CCH + c) * SEQL + idx[b * NSEL + i]] = emb[t];
}

extern "C" void kernel_launch(void* const* d_in, const int* in_sizes, int n_in,
                              void* d_out, int out_size, void* d_ws, size_t ws_size,
                              hipStream_t stream) {
  (void)in_sizes; (void)n_in; (void)ws_size;
  const float* x_skip    = (const float*)d_in[0];
  const float* attention = (const float*)d_in[1];
  const float* ln1_g = (const float*)d_in[2];
  const float* ln1_b = (const float*)d_in[3];
  const float* Wq    = (const float*)d_in[4];
  const float* Wk    = (const float*)d_in[5];
  const float* Wv    = (const float*)d_in[6];
  const float* Wrel  = (const float*)d_in[7];
  const float* rcb   = (const float*)d_in[8];
  const float* rpb   = (const float*)d_in[9];
  const float* Wo    = (const float*)d_in[10];
  const float* bo    = (const float*)d_in[11];
  const float* ln2_g = (const float*)d_in[12];
  const float* ln2_b = (const float*)d_in[13];
  const float* W1    = (const float*)d_in[14];
  const float* b1    = (const float*)d_in[15];
  const float* W2    = (const float*)d_in[16];
  const float* b2    = (const float*)d_in[17];
  float* out = (float*)d_out;
  char* ws = (char*)d_ws;

  unsigned short* E   = (unsigned short*)(ws + 0);    // 1,440,000
  int*      idx   = (int*)(ws + 1441792);             // 4,096
  float*    emb   = (float*)(ws + 1445888);           // 131,072
  float*    qc    = (float*)(ws + 1576960);           // 524,288
  unsigned short* kbT = (unsigned short*)(ws + 2101248); // 262,144
  unsigned short* vT  = (unsigned short*)(ws + 2363392); // 262,144
  float*    wb    = (float*)(ws + 2625536);           // 524,288
  float*    ob    = (float*)(ws + 3149824);           // 524,288
  int*      hist  = (int*)(ws + 3674112);             // 1,048,576
  int*      cnt   = (int*)(ws + 4722688);             // 64
  unsigned long long* cand = (unsigned long long*)(ws + 4722752); // 65,536
  int*      thr   = (int*)(ws + 4788288);             // 64  -> total ~4.8 MB

  hipMemsetAsync(d_out, 0, (size_t)out_size * sizeof(float), stream);
  hipMemsetAsync(ws + 3674112, 0, 1048576 + 64, stream);   // hist + cnt
  build_etab_kernel<<<(SEQL + 255) / 256, 256, 0, stream>>>(E);
  topk_hist_kernel<<<4 * TKB, 256, 0, stream>>>(attention, hist);
  topk_thresh_kernel<<<4, 1024, 0, stream>>>(hist, thr);
  topk_collect_kernel<<<4 * TKB, 256, 0, stream>>>(attention, thr, cand, cnt);
  topk_sortmerge_kernel<<<2, 1024, 0, stream>>>(cand, cnt, idx);
  gather_kernel<<<128, 256, 0, stream>>>(x_skip, idx, emb);
  for (int l = 0; l < 4; ++l) {
    qkv_kernel<<<256, 128, 0, stream>>>(emb, ln1_g, ln1_b, Wq, Wk, Wv,
                                        Wrel, rcb, rpb, qc, kbT, vT, wb, l);
    attn_kernel<<<1024, 256, 0, stream>>>(qc, kbT, vT, wb, E, idx, ob);
    mlp_kernel<<<256, 256, 0, stream>>>(ob, Wo, bo, ln2_g, ln2_b,
                                        W1, b1, W2, b2, emb, l);
  }
  scatter_kernel<<<128, 256, 0, stream>>>(emb, idx, out);
}

// Round 6
// 377.754 us; speedup vs baseline: 1.0678x; 1.0678x over previous
//
#include <hip/hip_runtime.h>
#include <math.h>

#define SEQL   45000
#define NBAT   2
#define CCH    32
#define NSEL   512
#define NHEAD  4
#define DKD    32
#define HDD    128
#define MLPD   512
#define EQCAP  2048
#define TKB    32     // scan blocks per (b,channel)

// bf16 helpers: round-to-nearest-even pack, cheap unpack (<<16)
__device__ inline unsigned short f2bf(float x) {
  unsigned u = __float_as_uint(x);
  u = (u + 0x7fffu + ((u >> 16) & 1u)) >> 16;
  return (unsigned short)u;
}
#define BFL(u) __uint_as_float((u) << 16)
#define BFH(u) __uint_as_float((u) & 0xffff0000u)

// ---------------- K0: basis feature table E[a][16] in bf16 ------------------
__global__ void build_etab_kernel(unsigned short* __restrict__ E) {
  int a = blockIdx.x * blockDim.x + threadIdx.x;
  if (a >= SEQL) return;
  float ad = (float)a;
  float out[16];
  float log2S = log2f((float)SEQL);
  #pragma unroll
  for (int k = 0; k < 5; ++k) {
    float hl = exp2f(3.0f + (float)k * (log2S - 3.0f) * 0.25f);
    out[k] = exp2f(-ad / hl);
  }
  const int cw[5] = {1, 3, 7, 15, 31};
  #pragma unroll
  for (int k = 0; k < 5; ++k) out[5 + k] = (a < cw[k]) ? 1.0f : 0.0f;
  float pmax = 0.0f;
  float pk[5];
  #pragma unroll
  for (int k = 0; k < 5; ++k) {
    float mean = 9000.0f * (float)(k + 1);
    float sd = 4500.0f;
    float cc = (mean / sd) * (mean / sd);      // 4,16,36,64,100
    float rr = mean / (sd * sd);
    float logz = lgammaf(cc) - cc * logf(rr);
    float p;
    if (a == 0) p = 1e-8f;                     // xlogy -> -inf -> exp = 0
    else p = expf((cc - 1.0f) * logf(ad) - rr * ad - logz) + 1e-8f;
    pk[k] = p;
    float mstar = (cc - 1.0f) / rr;            // 6750 .. 44550, in range
    float m0 = floorf(mstar), m1 = m0 + 1.0f;
    if (m1 > (float)(SEQL - 1)) m1 = (float)(SEQL - 1);
    float p0 = expf((cc - 1.0f) * logf(m0) - rr * m0 - logz) + 1e-8f;
    float p1 = expf((cc - 1.0f) * logf(m1) - rr * m1 - logz) + 1e-8f;
    pmax = fmaxf(pmax, fmaxf(p0, p1));
  }
  #pragma unroll
  for (int k = 0; k < 5; ++k) out[10 + k] = pk[k] / pmax;
  out[15] = 0.0f;
  uint4 o0, o1;
  o0.x = (unsigned)f2bf(out[0])  | ((unsigned)f2bf(out[1])  << 16);
  o0.y = (unsigned)f2bf(out[2])  | ((unsigned)f2bf(out[3])  << 16);
  o0.z = (unsigned)f2bf(out[4])  | ((unsigned)f2bf(out[5])  << 16);
  o0.w = (unsigned)f2bf(out[6])  | ((unsigned)f2bf(out[7])  << 16);
  o1.x = (unsigned)f2bf(out[8])  | ((unsigned)f2bf(out[9])  << 16);
  o1.y = (unsigned)f2bf(out[10]) | ((unsigned)f2bf(out[11]) << 16);
  o1.z = (unsigned)f2bf(out[12]) | ((unsigned)f2bf(out[13]) << 16);
  o1.w = (unsigned)f2bf(out[14]);
  uint4* E4 = (uint4*)(E + (size_t)a * 16);
  E4[0] = o0;
  E4[1] = o1;
}

// ---------------- top-k: two-level histogram threshold refinement -----------
// No value sort anywhere. Exact 32-bit threshold T32 + eq_take smallest-index
// ties. Selection set = {key > T32} ∪ {first eq_take indices with key == T32}.

// K1a: high-16 histogram, 128 blocks
__global__ __launch_bounds__(256) void topk_hist1_kernel(const float* __restrict__ att,
                                                         int* __restrict__ hist) {
  int ch4 = blockIdx.x / TKB;
  int blk = blockIdx.x % TKB;
  int b = ch4 >> 1, ch = ch4 & 1;
  const float* row = att + ((size_t)b * 3 + 1 + ch) * SEQL;
  int* h = hist + (size_t)ch4 * 65536;
  int per = (SEQL + TKB - 1) / TKB;
  int lo = blk * per;
  int hi = lo + per; if (hi > SEQL) hi = SEQL;
  for (int i = lo + threadIdx.x; i < hi; i += 256)
    atomicAdd(&h[__float_as_uint(row[i]) >> 16], 1);   // vals >= 0 -> monotone
}

// K1b: suffix-scan -> T16 and want (# to take from the ==T16 class)
__global__ __launch_bounds__(1024) void topk_thresh1_kernel(const int* __restrict__ hist,
                                                            int* __restrict__ thr16,
                                                            int* __restrict__ want2) {
  const int* h = hist + (size_t)blockIdx.x * 65536;
  __shared__ int s[1024];
  __shared__ int sh_t;
  int t = threadIdx.x;
  int base = t * 64;
  int loc[64];
  int sum = 0;
  #pragma unroll
  for (int i = 0; i < 16; ++i) {
    int4 v = ((const int4*)(h + base))[i];
    loc[i * 4 + 0] = v.x; loc[i * 4 + 1] = v.y;
    loc[i * 4 + 2] = v.z; loc[i * 4 + 3] = v.w;
    sum += v.x + v.y + v.z + v.w;
  }
  s[t] = sum;
  __syncthreads();
  for (int d = 1; d < 1024; d <<= 1) {
    int v = s[t] + ((t + d < 1024) ? s[t + d] : 0);
    __syncthreads();
    s[t] = v;
    __syncthreads();
  }
  int sufEx = (t == 1023) ? 0 : s[t + 1];
  if (s[t] >= 256 && sufEx < 256) sh_t = t;    // unique crossing chunk
  __syncthreads();
  if (t == sh_t) {
    int acc = sufEx;
    int T16 = base;
    int above = 0;
    for (int i = 63; i >= 0; --i) {
      acc += loc[i];
      if (acc >= 256) { T16 = base + i; above = acc - loc[i]; break; }
    }
    thr16[blockIdx.x] = T16;
    want2[blockIdx.x] = 256 - above;   // in [1,256]
  }
}

// K1c: low-16 histogram restricted to high16 == T16, 128 blocks
__global__ __launch_bounds__(256) void topk_hist2_kernel(const float* __restrict__ att,
                                                         const int* __restrict__ thr16,
                                                         int* __restrict__ hist2) {
  int ch4 = blockIdx.x / TKB;
  int blk = blockIdx.x % TKB;
  int b = ch4 >> 1, ch = ch4 & 1;
  const float* row = att + ((size_t)b * 3 + 1 + ch) * SEQL;
  unsigned T16 = (unsigned)thr16[ch4];
  int* h = hist2 + (size_t)ch4 * 65536;
  int per = (SEQL + TKB - 1) / TKB;
  int lo = blk * per;
  int hi = lo + per; if (hi > SEQL) hi = SEQL;
  for (int i = lo + threadIdx.x; i < hi; i += 256) {
    unsigned key = __float_as_uint(row[i]);
    if ((key >> 16) == T16) atomicAdd(&h[key & 0xffffu], 1);
  }
}

// K1d: suffix-scan of low-16 hist with target want2 -> T_low + eq_take
__global__ __launch_bounds__(1024) void topk_thresh2_kernel(const int* __restrict__ hist2,
                                                            const int* __restrict__ want2,
                                                            int* __restrict__ thrlow,
                                                            int* __restrict__ eqtake) {
  const int* h = hist2 + (size_t)blockIdx.x * 65536;
  int want = want2[blockIdx.x];
  __shared__ int s[1024];
  __shared__ int sh_t;
  int t = threadIdx.x;
  int base = t * 64;
  int loc[64];
  int sum = 0;
  #pragma unroll
  for (int i = 0; i < 16; ++i) {
    int4 v = ((const int4*)(h + base))[i];
    loc[i * 4 + 0] = v.x; loc[i * 4 + 1] = v.y;
    loc[i * 4 + 2] = v.z; loc[i * 4 + 3] = v.w;
    sum += v.x + v.y + v.z + v.w;
  }
  s[t] = sum;
  __syncthreads();
  for (int d = 1; d < 1024; d <<= 1) {
    int v = s[t] + ((t + d < 1024) ? s[t + d] : 0);
    __syncthreads();
    s[t] = v;
    __syncthreads();
  }
  int sufEx = (t == 1023) ? 0 : s[t + 1];
  if (s[t] >= want && sufEx < want) sh_t = t;
  __syncthreads();
  if (t == sh_t) {
    int acc = sufEx;
    int Tl = base;
    int above = 0;
    for (int i = 63; i >= 0; --i) {
      acc += loc[i];
      if (acc >= want) { Tl = base + i; above = acc - loc[i]; break; }
    }
    thrlow[blockIdx.x] = Tl;
    eqtake[blockIdx.x] = want - above;  // >= 1
  }
}

// K1e: collect sel (key > T32) and eq (key == T32), 128 blocks
__global__ __launch_bounds__(256) void topk_collect_kernel(
    const float* __restrict__ att, const int* __restrict__ thr16,
    const int* __restrict__ thrlow, int* __restrict__ sel,
    int* __restrict__ eqb, int* __restrict__ cnt_sel, int* __restrict__ cnt_eq) {
  int ch4 = blockIdx.x / TKB;
  int blk = blockIdx.x % TKB;
  int b = ch4 >> 1, ch = ch4 & 1;
  const float* row = att + ((size_t)b * 3 + 1 + ch) * SEQL;
  unsigned T32 = ((unsigned)thr16[ch4] << 16) | (unsigned)thrlow[ch4];
  int per = (SEQL + TKB - 1) / TKB;
  int lo = blk * per;
  int hi = lo + per; if (hi > SEQL) hi = SEQL;
  for (int i = lo + threadIdx.x; i < hi; i += 256) {
    unsigned key = __float_as_uint(row[i]);
    if (key > T32) {
      int p = atomicAdd(&cnt_sel[ch4], 1);
      if (p < 256) sel[ch4 * 256 + p] = i;
    } else if (key == T32) {
      int p = atomicAdd(&cnt_eq[ch4], 1);
      if (p < EQCAP) eqb[ch4 * EQCAP + p] = i;
    }
  }
}

// K1f: per batch — tiny runtime-sized eq sort (asc), assemble 512, sort asc
__global__ __launch_bounds__(1024) void topk_final_kernel(
    const int* __restrict__ sel, const int* __restrict__ eqb,
    const int* __restrict__ cnt_sel, const int* __restrict__ cnt_eq,
    const int* __restrict__ eqtake, int* __restrict__ idx) {
  __shared__ int m[512];
  __shared__ int eb[EQCAP];
  int b = blockIdx.x, t = threadIdx.x;
  for (int ch = 0; ch < 2; ++ch) {
    int ch4 = b * 2 + ch;
    int g = cnt_sel[ch4];            // == 256 - eqtake, < 256
    int take = eqtake[ch4];
    int ne = cnt_eq[ch4]; if (ne > EQCAP) ne = EQCAP;
    for (int i = t; i < g; i += 1024) m[ch * 256 + i] = sel[ch4 * 256 + i];
    int P = 2;
    while (P < ne) P <<= 1;          // pow2 pad (typical ne: 1-4)
    for (int i = t; i < P; i += 1024) eb[i] = (i < ne) ? eqb[ch4 * EQCAP + i] : 0x7fffffff;
    __syncthreads();
    for (int k = 2; k <= P; k <<= 1) {
      for (int j = k >> 1; j > 0; j >>= 1) {
        for (int i = t; i < P; i += 1024) {
          int ixj = i ^ j;
          if (ixj > i) {
            int va = eb[i], vb2 = eb[ixj];
            bool up = ((i & k) == 0);
            if ((va > vb2) == up) { eb[i] = vb2; eb[ixj] = va; }
          }
        }
        __syncthreads();
      }
    }
    for (int i = t; i < take; i += 1024) m[ch * 256 + g + i] = eb[i];
    __syncthreads();
  }
  // ascending 512 bitonic of merged indices
  for (int k = 2; k <= 512; k <<= 1) {
    for (int j = k >> 1; j > 0; j >>= 1) {
      if (t < 512) {
        int ixj = t ^ j;
        if (ixj > t) {
          int va = m[t], vb2 = m[ixj];
          bool up = ((t & k) == 0);
          if ((va > vb2) == up) { m[t] = vb2; m[ixj] = va; }
        }
      }
      __syncthreads();
    }
  }
  if (t < 512) idx[b * 512 + t] = m[t];
}

// ---------------- K2: gather emb rows ---------------------------------------
__global__ void gather_kernel(const float* __restrict__ x, const int* __restrict__ idx,
                              float* __restrict__ emb) {
  int t = blockIdx.x * 256 + threadIdx.x;
  if (t >= NBAT * NSEL * CCH) return;
  int c = t & 31;
  int i = (t >> 5) & 511;
  int b = t >> 14;
  emb[t] = x[((size_t)b * CCH + c) * SEQL + idx[b * NSEL + i]];
}

// ---------------- K3: LN1 + QKV + rel-weight factorization ------------------
// kbT/vT layout (bf16): [((b*4+h)*4+dpack)*4096 + i*8 + (d&7)]
__global__ __launch_bounds__(128) void qkv_kernel(
    const float* __restrict__ emb,
    const float* __restrict__ ln_g, const float* __restrict__ ln_b,
    const float* __restrict__ Wq, const float* __restrict__ Wk,
    const float* __restrict__ Wv, const float* __restrict__ Wrel,
    const float* __restrict__ rcb, const float* __restrict__ rpb,
    float* __restrict__ qc, unsigned short* __restrict__ kbT,
    unsigned short* __restrict__ vT, float* __restrict__ wb, int layer) {
  __shared__ float qs[4][128];
  int hd = threadIdx.x;        // 0..127
  int hh = hd >> 5, d = hd & 31;
  const float* g = ln_g + layer * CCH;
  const float* bb = ln_b + layer * CCH;
  const float* wq = Wq + (size_t)layer * CCH * HDD + hd;
  const float* wk = Wk + (size_t)layer * CCH * HDD + hd;
  const float* wv = Wv + (size_t)layer * CCH * HDD + hd;
  #pragma unroll
  for (int r = 0; r < 4; ++r) {
    int row = blockIdx.x * 4 + r;          // b*512 + i
    int b = row >> 9, ii = row & 511;
    const float* e = emb + (size_t)row * CCH;
    float h[32];
    float mu = 0.f;
    #pragma unroll
    for (int c = 0; c < 32; ++c) { h[c] = e[c]; mu += h[c]; }
    mu *= (1.0f / 32.0f);
    float var = 0.f;
    #pragma unroll
    for (int c = 0; c < 32; ++c) { float dd0 = h[c] - mu; var += dd0 * dd0; }
    var *= (1.0f / 32.0f);
    float rstd = rsqrtf(var + 1e-5f);
    #pragma unroll
    for (int c = 0; c < 32; ++c) h[c] = (h[c] - mu) * rstd * g[c] + bb[c];
    float q = 0.f, kk = 0.f, vv = 0.f;
    #pragma unroll
    for (int c = 0; c < 32; ++c) {
      q += h[c] * wq[c * HDD];
      kk += h[c] * wk[c * HDD];
      vv += h[c] * wv[c * HDD];
    }
    q *= 0.17677669529663687f;   // DK^-0.5
    qs[r][hd] = q;
    qc[(size_t)row * HDD + hd] = q + rcb[(layer * NHEAD + hh) * DKD + d];
    size_t tpos = ((size_t)(b * 4 + hh) * 4 + (d >> 3)) * 4096 + (size_t)ii * 8 + (d & 7);
    kbT[tpos] = f2bf(kk);
    vT[tpos]  = f2bf(vv);
    __syncthreads();
    if (hd < 120) {
      int h2 = hd / 30, f = hd % 30;
      const float* wr = Wrel + ((size_t)layer * 30 + f) * HDD + h2 * DKD;
      const float* rp = rpb + (layer * NHEAD + h2) * DKD;
      const float* qsh = qs[r] + h2 * DKD;
      float acc = 0.f;
      #pragma unroll
      for (int dd = 0; dd < 32; ++dd) acc += (qsh[dd] + rp[dd]) * wr[dd];
      wb[((size_t)row * NHEAD + h2) * 32 + f] = acc;   // padded stride 32
    }
  }
}

// ---------------- K4: attention (content + rel + softmax + PV) --------------
// 1024 blocks (b, h, 4 i-rows), 4 waves, 1 row/wave. All-coalesced:
// k AND v via transposed bf16 layout; softmax p stays in registers.
__global__ __launch_bounds__(256, 4) void attn_kernel(
    const float* __restrict__ qc, const unsigned short* __restrict__ kbT,
    const unsigned short* __restrict__ vT, const float* __restrict__ wbuf,
    const unsigned short* __restrict__ E, const int* __restrict__ idx,
    float* __restrict__ ob) {
  __shared__ int idxl[512];
  int bid = blockIdx.x;
  int b = bid >> 9;
  int h = (bid >> 7) & 3;
  int i0 = (bid & 127) * 4;
  int tid = threadIdx.x;
  int wv = tid >> 6, ln = tid & 63;
  for (int i = tid; i < 512; i += 256) idxl[i] = idx[b * NSEL + i];
  __syncthreads();
  int i = i0 + wv;
  const float* qrow = qc + (size_t)(b * NSEL + i) * HDD + h * DKD;
  float q[32];
  #pragma unroll
  for (int d4 = 0; d4 < 8; ++d4) {
    float4 qv = *(const float4*)(qrow + d4 * 4);
    q[d4 * 4 + 0] = qv.x; q[d4 * 4 + 1] = qv.y;
    q[d4 * 4 + 2] = qv.z; q[d4 * 4 + 3] = qv.w;
  }
  const float* wrow = wbuf + ((size_t)(b * NSEL + i) * NHEAD + h) * 32;
  float w0[15], w1[15];
  #pragma unroll
  for (int f = 0; f < 15; ++f) { w0[f] = wrow[f]; w1[f] = wrow[15 + f]; }
  int ii = idxl[i];
  const uint4* kb4 = (const uint4*)kbT + (size_t)(b * 4 + h) * 4 * 512;
  const uint4* vb4 = (const uint4*)vT + (size_t)(b * 4 + h) * 4 * 512;
  float lg[8];
  #pragma unroll
  for (int u = 0; u < 8; ++u) {
    int j = u * 64 + ln;
    int dj = ii - idxl[j];
    float cacc = 0.f;
    #pragma unroll
    for (int dp = 0; dp < 4; ++dp) {
      uint4 kv = kb4[dp * 512 + j];
      cacc += q[dp * 8 + 0] * BFL(kv.x) + q[dp * 8 + 1] * BFH(kv.x)
            + q[dp * 8 + 2] * BFL(kv.y) + q[dp * 8 + 3] * BFH(kv.y)
            + q[dp * 8 + 4] * BFL(kv.z) + q[dp * 8 + 5] * BFH(kv.z)
            + q[dp * 8 + 6] * BFL(kv.w) + q[dp * 8 + 7] * BFH(kv.w);
    }
    int a = dj < 0 ? -dj : dj;
    const uint4* er = (const uint4*)(E + (size_t)a * 16);
    uint4 e0 = er[0], e1 = er[1];
    float r0 = BFL(e0.x) * w0[0]  + BFH(e0.x) * w0[1]
             + BFL(e0.y) * w0[2]  + BFH(e0.y) * w0[3]
             + BFL(e0.z) * w0[4]  + BFH(e0.z) * w0[5]
             + BFL(e0.w) * w0[6]  + BFH(e0.w) * w0[7]
             + BFL(e1.x) * w0[8]  + BFH(e1.x) * w0[9]
             + BFL(e1.y) * w0[10] + BFH(e1.y) * w0[11]
             + BFL(e1.z) * w0[12] + BFH(e1.z) * w0[13]
             + BFL(e1.w) * w0[14];
    float r1 = BFL(e0.x) * w1[0]  + BFH(e0.x) * w1[1]
             + BFL(e0.y) * w1[2]  + BFH(e0.y) * w1[3]
             + BFL(e0.z) * w1[4]  + BFH(e0.z) * w1[5]
             + BFL(e0.w) * w1[6]  + BFH(e0.w) * w1[7]
             + BFL(e1.x) * w1[8]  + BFH(e1.x) * w1[9]
             + BFL(e1.y) * w1[10] + BFH(e1.y) * w1[11]
             + BFL(e1.z) * w1[12] + BFH(e1.z) * w1[13]
             + BFL(e1.w) * w1[14];
    float sgn = dj > 0 ? 1.f : (dj < 0 ? -1.f : 0.f);
    lg[u] = cacc + r0 + sgn * r1;
  }
  // full-row softmax across the wave (512 logits, 8/lane), in registers
  float m = lg[0];
  #pragma unroll
  for (int u = 1; u < 8; ++u) m = fmaxf(m, lg[u]);
  #pragma unroll
  for (int s = 1; s < 64; s <<= 1) m = fmaxf(m, __shfl_xor(m, s));
  float ssum = 0.f;
  #pragma unroll
  for (int u = 0; u < 8; ++u) { lg[u] = expf(lg[u] - m); ssum += lg[u]; }
  #pragma unroll
  for (int s = 1; s < 64; s <<= 1) ssum += __shfl_xor(ssum, s);
  float invs = 1.0f / ssum;
  // PV: p in registers, v coalesced; butterfly-reduce 8 partial d-sums
  float* obrow = ob + (size_t)(b * NSEL + i) * HDD + h * DKD;
  #pragma unroll
  for (int dp = 0; dp < 4; ++dp) {
    float acc[8] = {0.f, 0.f, 0.f, 0.f, 0.f, 0.f, 0.f, 0.f};
    #pragma unroll
    for (int u = 0; u < 8; ++u) {
      uint4 vv = vb4[dp * 512 + u * 64 + ln];
      float p = lg[u];
      acc[0] += p * BFL(vv.x); acc[1] += p * BFH(vv.x);
      acc[2] += p * BFL(vv.y); acc[3] += p * BFH(vv.y);
      acc[4] += p * BFL(vv.z); acc[5] += p * BFH(vv.z);
      acc[6] += p * BFL(vv.w); acc[7] += p * BFH(vv.w);
    }
    #pragma unroll
    for (int s = 1; s < 64; s <<= 1) {
      #pragma unroll
      for (int t = 0; t < 8; ++t) acc[t] += __shfl_xor(acc[t], s);
    }
    int sel = ln & 7;
    float oval = acc[0];
    #pragma unroll
    for (int t = 1; t < 8; ++t) oval = (sel == t) ? acc[t] : oval;
    if (ln < 8) obrow[dp * 8 + ln] = oval * invs;
  }
}

// ---------------- K5: fused proj+residual+LN2+MLP+residual, 4 rows/block ----
__global__ __launch_bounds__(256) void mlp_kernel(
    const float* __restrict__ ob, const float* __restrict__ Wo,
    const float* __restrict__ bo,
    const float* __restrict__ ln_g, const float* __restrict__ ln_b,
    const float* __restrict__ W1, const float* __restrict__ b1,
    const float* __restrict__ W2, const float* __restrict__ b2,
    float* __restrict__ emb, int layer) {
  __shared__ float part[4][8][32];
  __shared__ float res[4][32];
  __shared__ float hln[4][32];
  __shared__ float a1s[4][MLPD];
  int row0 = blockIdx.x * 4;
  int tid = threadIdx.x;
  int c = tid & 31, seg = tid >> 5;
  const float* wo = Wo + (size_t)layer * HDD * CCH + c;
  float pacc[4] = {0.f, 0.f, 0.f, 0.f};
  #pragma unroll
  for (int k = 0; k < 16; ++k) {
    int kk = seg * 16 + k;
    float w = wo[kk * CCH];
    #pragma unroll
    for (int r = 0; r < 4; ++r)
      pacc[r] += ob[(size_t)(row0 + r) * HDD + kk] * w;
  }
  #pragma unroll
  for (int r = 0; r < 4; ++r) part[r][seg][c] = pacc[r];
  __syncthreads();
  if (tid < 128) {
    int r = tid >> 5, cc = tid & 31;
    float s = bo[layer * CCH + cc] + emb[(size_t)(row0 + r) * CCH + cc];
    #pragma unroll
    for (int sg = 0; sg < 8; ++sg) s += part[r][sg][cc];
    res[r][cc] = s;
  }
  __syncthreads();
  if (tid < 128) {
    int r = tid >> 5, cc = tid & 31;
    float mu = 0.f, s2 = 0.f;
    #pragma unroll
    for (int c2 = 0; c2 < 32; ++c2) { float v = res[r][c2]; mu += v; s2 += v * v; }
    mu *= (1.0f / 32.0f);
    float var = s2 * (1.0f / 32.0f) - mu * mu;
    float rstd = rsqrtf(var + 1e-5f);
    hln[r][cc] = (res[r][cc] - mu) * rstd * ln_g[layer * CCH + cc] + ln_b[layer * CCH + cc];
  }
  __syncthreads();
  const float* w1 = W1 + (size_t)layer * CCH * MLPD;
  float accA[4], accB[4];
  float bA = b1[layer * MLPD + tid], bB = b1[layer * MLPD + tid + 256];
  #pragma unroll
  for (int r = 0; r < 4; ++r) { accA[r] = bA; accB[r] = bB; }
  for (int c2 = 0; c2 < 32; ++c2) {
    float wa = w1[c2 * MLPD + tid];
    float wb2 = w1[c2 * MLPD + tid + 256];
    #pragma unroll
    for (int r = 0; r < 4; ++r) {
      float hv = hln[r][c2];
      accA[r] += hv * wa;
      accB[r] += hv * wb2;
    }
  }
  #pragma unroll
  for (int r = 0; r < 4; ++r) {
    a1s[r][tid]       = 0.5f * accA[r] * (1.0f + erff(accA[r] * 0.70710678118654752f));
    a1s[r][tid + 256] = 0.5f * accB[r] * (1.0f + erff(accB[r] * 0.70710678118654752f));
  }
  __syncthreads();
  const float* w2 = W2 + (size_t)layer * MLPD * CCH;
  float acc2[4] = {0.f, 0.f, 0.f, 0.f};
  #pragma unroll 4
  for (int mi = 0; mi < 64; ++mi) {
    int m = seg * 64 + mi;
    float w = w2[m * CCH + c];
    #pragma unroll
    for (int r = 0; r < 4; ++r) acc2[r] += a1s[r][m] * w;
  }
  __syncthreads();                    // part[] reuse
  #pragma unroll
  for (int r = 0; r < 4; ++r) part[r][seg][c] = acc2[r];
  __syncthreads();
  if (tid < 128) {
    int r = tid >> 5, cc = tid & 31;
    float s = b2[layer * CCH + cc] + res[r][cc];
    #pragma unroll
    for (int sg = 0; sg < 8; ++sg) s += part[r][sg][cc];
    emb[(size_t)(row0 + r) * CCH + cc] = s;
  }
}

// ---------------- K7: scatter back ------------------------------------------
__global__ void scatter_kernel(const float* __restrict__ emb, const int* __restrict__ idx,
                               float* __restrict__ out) {
  int t = blockIdx.x * 256 + threadIdx.x;
  if (t >= NBAT * NSEL * CCH) return;
  int c = t & 31;
  int i = (t >> 5) & 511;
  int b = t >> 14;
  out[((size_t)b * CCH + c) * SEQL + idx[b * NSEL + i]] = emb[t];
}

extern "C" void kernel_launch(void* const* d_in, const int* in_sizes, int n_in,
                              void* d_out, int out_size, void* d_ws, size_t ws_size,
                              hipStream_t stream) {
  (void)in_sizes; (void)n_in; (void)ws_size;
  const float* x_skip    = (const float*)d_in[0];
  const float* attention = (const float*)d_in[1];
  const float* ln1_g = (const float*)d_in[2];
  const float* ln1_b = (const float*)d_in[3];
  const float* Wq    = (const float*)d_in[4];
  const float* Wk    = (const float*)d_in[5];
  const float* Wv    = (const float*)d_in[6];
  const float* Wrel  = (const float*)d_in[7];
  const float* rcb   = (const float*)d_in[8];
  const float* rpb   = (const float*)d_in[9];
  const float* Wo    = (const float*)d_in[10];
  const float* bo    = (const float*)d_in[11];
  const float* ln2_g = (const float*)d_in[12];
  const float* ln2_b = (const float*)d_in[13];
  const float* W1    = (const float*)d_in[14];
  const float* b1    = (const float*)d_in[15];
  const float* W2    = (const float*)d_in[16];
  const float* b2    = (const float*)d_in[17];
  float* out = (float*)d_out;
  char* ws = (char*)d_ws;

  unsigned short* E   = (unsigned short*)(ws + 0);    // 1,440,000
  int*      idx   = (int*)(ws + 1441792);             // 4,096
  float*    emb   = (float*)(ws + 1445888);           // 131,072
  float*    qc    = (float*)(ws + 1576960);           // 524,288
  unsigned short* kbT = (unsigned short*)(ws + 2101248); // 262,144
  unsigned short* vT  = (unsigned short*)(ws + 2363392); // 262,144
  float*    wb    = (float*)(ws + 2625536);           // 524,288
  float*    ob    = (float*)(ws + 3149824);           // 524,288
  int*      hist1 = (int*)(ws + 3674112);             // 1,048,576
  int*      hist2 = (int*)(ws + 4722688);             // 1,048,576
  int*      cnt_sel = (int*)(ws + 5771264);           // 16
  int*      cnt_eq  = (int*)(ws + 5771280);           // 16
  int*      thr16   = (int*)(ws + 5771296);           // 16
  int*      want2   = (int*)(ws + 5771312);           // 16
  int*      thrlow  = (int*)(ws + 5771328);           // 16
  int*      eqtake  = (int*)(ws + 5771344);           // 16
  int*      sel     = (int*)(ws + 5771360);           // 4*256*4 = 4,096
  int*      eqb     = (int*)(ws + 5775456);           // 4*2048*4 = 32,768 -> ~5.81 MB

  hipMemsetAsync(d_out, 0, (size_t)out_size * sizeof(float), stream);
  hipMemsetAsync(ws + 3674112, 0, 2097152 + 32, stream);  // hist1+hist2+cnts
  build_etab_kernel<<<(SEQL + 255) / 256, 256, 0, stream>>>(E);
  topk_hist1_kernel<<<4 * TKB, 256, 0, stream>>>(attention, hist1);
  topk_thresh1_kernel<<<4, 1024, 0, stream>>>(hist1, thr16, want2);
  topk_hist2_kernel<<<4 * TKB, 256, 0, stream>>>(attention, thr16, hist2);
  topk_thresh2_kernel<<<4, 1024, 0, stream>>>(hist2, want2, thrlow, eqtake);
  topk_collect_kernel<<<4 * TKB, 256, 0, stream>>>(attention, thr16, thrlow,
                                                   sel, eqb, cnt_sel, cnt_eq);
  topk_final_kernel<<<2, 1024, 0, stream>>>(sel, eqb, cnt_sel, cnt_eq, eqtake, idx);
  gather_kernel<<<128, 256, 0, stream>>>(x_skip, idx, emb);
  for (int l = 0; l < 4; ++l) {
    qkv_kernel<<<256, 128, 0, stream>>>(emb, ln1_g, ln1_b, Wq, Wk, Wv,
                                        Wrel, rcb, rpb, qc, kbT, vT, wb, l);
    attn_kernel<<<1024, 256, 0, stream>>>(qc, kbT, vT, wb, E, idx, ob);
    mlp_kernel<<<256, 256, 0, stream>>>(ob, Wo, bo, ln2_g, ln2_b,
                                        W1, b1, W2, b2, emb, l);
  }
  scatter_kernel<<<128, 256, 0, stream>>>(emb, idx, out);
}

// Round 7
// 357.839 us; speedup vs baseline: 1.1272x; 1.0557x over previous
//
#include <hip/hip_runtime.h>
#include <math.h>

#define SEQL   45000
#define NBAT   2
#define CCH    32
#define NSEL   512
#define NHEAD  4
#define DKD    32
#define HDD    128
#define MLPD   512
#define CDCAP  2048
#define TKB    32     // scan blocks per (b,channel)
#define ETB    176    // etab blocks = ceil(45000/256)

// bf16 helpers: round-to-nearest-even pack, cheap unpack (<<16)
__device__ inline unsigned short f2bf(float x) {
  unsigned u = __float_as_uint(x);
  u = (u + 0x7fffu + ((u >> 16) & 1u)) >> 16;
  return (unsigned short)u;
}
#define BFL(u) __uint_as_float((u) << 16)
#define BFH(u) __uint_as_float((u) & 0xffff0000u)

// ---------------- K0: fused etab-build (blocks 0..175) + high16 histogram ---
__global__ __launch_bounds__(256) void prep_kernel(const float* __restrict__ att,
                                                   unsigned short* __restrict__ E,
                                                   int* __restrict__ hist) {
  if (blockIdx.x < ETB) {
    int a = blockIdx.x * 256 + threadIdx.x;
    if (a >= SEQL) return;
    float ad = (float)a;
    float out[16];
    float log2S = log2f((float)SEQL);
    #pragma unroll
    for (int k = 0; k < 5; ++k) {
      float hl = exp2f(3.0f + (float)k * (log2S - 3.0f) * 0.25f);
      out[k] = exp2f(-ad / hl);
    }
    const int cw[5] = {1, 3, 7, 15, 31};
    #pragma unroll
    for (int k = 0; k < 5; ++k) out[5 + k] = (a < cw[k]) ? 1.0f : 0.0f;
    float pmax = 0.0f;
    float pk[5];
    #pragma unroll
    for (int k = 0; k < 5; ++k) {
      float mean = 9000.0f * (float)(k + 1);
      float sd = 4500.0f;
      float cc = (mean / sd) * (mean / sd);      // 4,16,36,64,100
      float rr = mean / (sd * sd);
      float logz = lgammaf(cc) - cc * logf(rr);
      float p;
      if (a == 0) p = 1e-8f;                     // xlogy -> -inf -> exp = 0
      else p = expf((cc - 1.0f) * logf(ad) - rr * ad - logz) + 1e-8f;
      pk[k] = p;
      float mstar = (cc - 1.0f) / rr;            // 6750 .. 44550, in range
      float m0 = floorf(mstar), m1 = m0 + 1.0f;
      if (m1 > (float)(SEQL - 1)) m1 = (float)(SEQL - 1);
      float p0 = expf((cc - 1.0f) * logf(m0) - rr * m0 - logz) + 1e-8f;
      float p1 = expf((cc - 1.0f) * logf(m1) - rr * m1 - logz) + 1e-8f;
      pmax = fmaxf(pmax, fmaxf(p0, p1));
    }
    #pragma unroll
    for (int k = 0; k < 5; ++k) out[10 + k] = pk[k] / pmax;
    out[15] = 0.0f;
    uint4 o0, o1;
    o0.x = (unsigned)f2bf(out[0])  | ((unsigned)f2bf(out[1])  << 16);
    o0.y = (unsigned)f2bf(out[2])  | ((unsigned)f2bf(out[3])  << 16);
    o0.z = (unsigned)f2bf(out[4])  | ((unsigned)f2bf(out[5])  << 16);
    o0.w = (unsigned)f2bf(out[6])  | ((unsigned)f2bf(out[7])  << 16);
    o1.x = (unsigned)f2bf(out[8])  | ((unsigned)f2bf(out[9])  << 16);
    o1.y = (unsigned)f2bf(out[10]) | ((unsigned)f2bf(out[11]) << 16);
    o1.z = (unsigned)f2bf(out[12]) | ((unsigned)f2bf(out[13]) << 16);
    o1.w = (unsigned)f2bf(out[14]);
    uint4* E4 = (uint4*)(E + (size_t)a * 16);
    E4[0] = o0;
    E4[1] = o1;
  } else {
    int bid = blockIdx.x - ETB;
    int ch4 = bid / TKB;
    int blk = bid % TKB;
    int b = ch4 >> 1, ch = ch4 & 1;
    const float* row = att + ((size_t)b * 3 + 1 + ch) * SEQL;
    int* h = hist + (size_t)ch4 * 65536;
    int per = (SEQL + TKB - 1) / TKB;
    int lo = blk * per;
    int hi = lo + per; if (hi > SEQL) hi = SEQL;
    for (int i = lo + threadIdx.x; i < hi; i += 256)
      atomicAdd(&h[__float_as_uint(row[i]) >> 16], 1);  // vals >= 0 -> monotone
  }
}

// ---------------- K1b: suffix-scan -> T16 (count(key>=T16) in [256, 256+bin))
__global__ __launch_bounds__(1024) void topk_thresh_kernel(const int* __restrict__ hist,
                                                           int* __restrict__ thr16) {
  const int* h = hist + (size_t)blockIdx.x * 65536;
  __shared__ int s[1024];
  __shared__ int sh_t;
  int t = threadIdx.x;
  int base = t * 64;
  int loc[64];
  int sum = 0;
  #pragma unroll
  for (int i = 0; i < 16; ++i) {
    int4 v = ((const int4*)(h + base))[i];
    loc[i * 4 + 0] = v.x; loc[i * 4 + 1] = v.y;
    loc[i * 4 + 2] = v.z; loc[i * 4 + 3] = v.w;
    sum += v.x + v.y + v.z + v.w;
  }
  s[t] = sum;
  __syncthreads();
  for (int d = 1; d < 1024; d <<= 1) {
    int v = s[t] + ((t + d < 1024) ? s[t + d] : 0);
    __syncthreads();
    s[t] = v;
    __syncthreads();
  }
  int sufEx = (t == 1023) ? 0 : s[t + 1];
  if (s[t] >= 256 && sufEx < 256) sh_t = t;    // unique crossing chunk
  __syncthreads();
  if (t == sh_t) {
    int acc = sufEx;
    int T16 = base;
    for (int i = 63; i >= 0; --i) {
      acc += loc[i];
      if (acc >= 256) { T16 = base + i; break; }
    }
    thr16[blockIdx.x] = T16;
  }
}

// ---------------- K1c: collect candidates (key>>16 >= T16) as u64 -----------
__global__ __launch_bounds__(256) void topk_collect_kernel(
    const float* __restrict__ att, const int* __restrict__ thr16,
    unsigned long long* __restrict__ cand, int* __restrict__ cnt) {
  int ch4 = blockIdx.x / TKB;
  int blk = blockIdx.x % TKB;
  int b = ch4 >> 1, ch = ch4 & 1;
  const float* row = att + ((size_t)b * 3 + 1 + ch) * SEQL;
  unsigned T16 = (unsigned)thr16[ch4];
  int per = (SEQL + TKB - 1) / TKB;
  int lo = blk * per;
  int hi = lo + per; if (hi > SEQL) hi = SEQL;
  for (int i = lo + threadIdx.x; i < hi; i += 256) {
    unsigned key = __float_as_uint(row[i]);
    if ((key >> 16) >= T16) {
      int p = atomicAdd(&cnt[ch4], 1);
      if (p < CDCAP)
        cand[(size_t)ch4 * CDCAP + p] =
            ((unsigned long long)key << 32) | (unsigned)(~(unsigned)i);
    }
  }
}

// ---------------- K1d: per batch — sort cands desc (P=next pow2), merge -----
// Desc u64 order = value desc, then larger ~i = smaller index: exact argsort ties.
__global__ __launch_bounds__(1024) void topk_final_kernel(
    const unsigned long long* __restrict__ cand, const int* __restrict__ cnt,
    int* __restrict__ idx) {
  __shared__ unsigned long long sc[CDCAP];
  __shared__ int m[512];
  int b = blockIdx.x, t = threadIdx.x;
  for (int ch = 0; ch < 2; ++ch) {
    int ch4 = b * 2 + ch;
    int n = cnt[ch4]; if (n > CDCAP) n = CDCAP;   // n >= 256 by construction
    int P = 256;
    while (P < n) P <<= 1;                        // typical: 512
    for (int i = t; i < P; i += 1024)
      sc[i] = (i < n) ? cand[(size_t)ch4 * CDCAP + i] : 0ull;  // 0 sorts last
    __syncthreads();
    for (int k = 2; k <= P; k <<= 1) {
      for (int j = k >> 1; j > 0; j >>= 1) {
        for (int i = t; i < P; i += 1024) {
          int ixj = i ^ j;
          if (ixj > i) {
            unsigned long long va = sc[i], vb2 = sc[ixj];
            bool up = ((i & k) == 0);
            if ((va < vb2) == up) { sc[i] = vb2; sc[ixj] = va; }
          }
        }
        __syncthreads();
      }
    }
    if (t < 256)
      m[ch * 256 + t] = (int)~(unsigned)(sc[t] & 0xFFFFFFFFull);
    __syncthreads();
  }
  // ascending 512 bitonic of merged indices
  for (int k = 2; k <= 512; k <<= 1) {
    for (int j = k >> 1; j > 0; j >>= 1) {
      if (t < 512) {
        int ixj = t ^ j;
        if (ixj > t) {
          int va = m[t], vb2 = m[ixj];
          bool up = ((t & k) == 0);
          if ((va > vb2) == up) { m[t] = vb2; m[ixj] = va; }
        }
      }
      __syncthreads();
    }
  }
  if (t < 512) idx[b * 512 + t] = m[t];
}

// ---------------- K2: gather emb rows ---------------------------------------
__global__ void gather_kernel(const float* __restrict__ x, const int* __restrict__ idx,
                              float* __restrict__ emb) {
  int t = blockIdx.x * 256 + threadIdx.x;
  if (t >= NBAT * NSEL * CCH) return;
  int c = t & 31;
  int i = (t >> 5) & 511;
  int b = t >> 14;
  emb[t] = x[((size_t)b * CCH + c) * SEQL + idx[b * NSEL + i]];
}

// ---------------- K3: LN1 + QKV + rel-weight factorization ------------------
// ONE row per 128-thr block, grid 1024 -> 4 blocks/CU (was 1): latency hiding
// for the strided weight reads. kbT/vT (bf16): [((b*4+h)*4+dpack)*4096+i*8+(d&7)]
__global__ __launch_bounds__(128) void qkv_kernel(
    const float* __restrict__ emb,
    const float* __restrict__ ln_g, const float* __restrict__ ln_b,
    const float* __restrict__ Wq, const float* __restrict__ Wk,
    const float* __restrict__ Wv, const float* __restrict__ Wrel,
    const float* __restrict__ rcb, const float* __restrict__ rpb,
    float* __restrict__ qc, unsigned short* __restrict__ kbT,
    unsigned short* __restrict__ vT, float* __restrict__ wb, int layer) {
  __shared__ float qs[128];
  int hd = threadIdx.x;        // 0..127
  int hh = hd >> 5, d = hd & 31;
  int row = blockIdx.x;        // b*512 + i
  int b = row >> 9, ii = row & 511;
  const float* g = ln_g + layer * CCH;
  const float* bb = ln_b + layer * CCH;
  const float* e = emb + (size_t)row * CCH;
  float h[32];
  float mu = 0.f;
  #pragma unroll
  for (int c = 0; c < 32; ++c) { h[c] = e[c]; mu += h[c]; }
  mu *= (1.0f / 32.0f);
  float var = 0.f;
  #pragma unroll
  for (int c = 0; c < 32; ++c) { float dd0 = h[c] - mu; var += dd0 * dd0; }
  var *= (1.0f / 32.0f);
  float rstd = rsqrtf(var + 1e-5f);
  #pragma unroll
  for (int c = 0; c < 32; ++c) h[c] = (h[c] - mu) * rstd * g[c] + bb[c];
  const float* wq = Wq + (size_t)layer * CCH * HDD + hd;
  const float* wk = Wk + (size_t)layer * CCH * HDD + hd;
  const float* wv = Wv + (size_t)layer * CCH * HDD + hd;
  float q = 0.f, kk = 0.f, vv = 0.f;
  #pragma unroll
  for (int c = 0; c < 32; ++c) {
    q += h[c] * wq[c * HDD];
    kk += h[c] * wk[c * HDD];
    vv += h[c] * wv[c * HDD];
  }
  q *= 0.17677669529663687f;   // DK^-0.5
  qs[hd] = q;
  qc[(size_t)row * HDD + hd] = q + rcb[(layer * NHEAD + hh) * DKD + d];
  size_t tpos = ((size_t)(b * 4 + hh) * 4 + (d >> 3)) * 4096 + (size_t)ii * 8 + (d & 7);
  kbT[tpos] = f2bf(kk);
  vT[tpos]  = f2bf(vv);
  __syncthreads();
  if (hd < 120) {
    int h2 = hd / 30, f = hd % 30;
    const float* wr = Wrel + ((size_t)layer * 30 + f) * HDD + h2 * DKD;
    const float* rp = rpb + (layer * NHEAD + h2) * DKD;
    const float* qsh = qs + h2 * DKD;
    float acc = 0.f;
    #pragma unroll
    for (int dd = 0; dd < 32; ++dd) acc += (qsh[dd] + rp[dd]) * wr[dd];
    wb[((size_t)row * NHEAD + h2) * 32 + f] = acc;   // padded stride 32
  }
}

// ---------------- K4: attention (content + rel + softmax + PV) --------------
// 1024 blocks (b, h, 4 i-rows), 4 waves, 1 row/wave. All-coalesced:
// k AND v via transposed bf16 layout; softmax p stays in registers.
__global__ __launch_bounds__(256, 4) void attn_kernel(
    const float* __restrict__ qc, const unsigned short* __restrict__ kbT,
    const unsigned short* __restrict__ vT, const float* __restrict__ wbuf,
    const unsigned short* __restrict__ E, const int* __restrict__ idx,
    float* __restrict__ ob) {
  __shared__ int idxl[512];
  int bid = blockIdx.x;
  int b = bid >> 9;
  int h = (bid >> 7) & 3;
  int i0 = (bid & 127) * 4;
  int tid = threadIdx.x;
  int wv = tid >> 6, ln = tid & 63;
  for (int i = tid; i < 512; i += 256) idxl[i] = idx[b * NSEL + i];
  __syncthreads();
  int i = i0 + wv;
  const float* qrow = qc + (size_t)(b * NSEL + i) * HDD + h * DKD;
  float q[32];
  #pragma unroll
  for (int d4 = 0; d4 < 8; ++d4) {
    float4 qv = *(const float4*)(qrow + d4 * 4);
    q[d4 * 4 + 0] = qv.x; q[d4 * 4 + 1] = qv.y;
    q[d4 * 4 + 2] = qv.z; q[d4 * 4 + 3] = qv.w;
  }
  const float* wrow = wbuf + ((size_t)(b * NSEL + i) * NHEAD + h) * 32;
  float w0[15], w1[15];
  #pragma unroll
  for (int f = 0; f < 15; ++f) { w0[f] = wrow[f]; w1[f] = wrow[15 + f]; }
  int ii = idxl[i];
  const uint4* kb4 = (const uint4*)kbT + (size_t)(b * 4 + h) * 4 * 512;
  const uint4* vb4 = (const uint4*)vT + (size_t)(b * 4 + h) * 4 * 512;
  float lg[8];
  #pragma unroll
  for (int u = 0; u < 8; ++u) {
    int j = u * 64 + ln;
    int dj = ii - idxl[j];
    float cacc = 0.f;
    #pragma unroll
    for (int dp = 0; dp < 4; ++dp) {
      uint4 kv = kb4[dp * 512 + j];
      cacc += q[dp * 8 + 0] * BFL(kv.x) + q[dp * 8 + 1] * BFH(kv.x)
            + q[dp * 8 + 2] * BFL(kv.y) + q[dp * 8 + 3] * BFH(kv.y)
            + q[dp * 8 + 4] * BFL(kv.z) + q[dp * 8 + 5] * BFH(kv.z)
            + q[dp * 8 + 6] * BFL(kv.w) + q[dp * 8 + 7] * BFH(kv.w);
    }
    int a = dj < 0 ? -dj : dj;
    const uint4* er = (const uint4*)(E + (size_t)a * 16);
    uint4 e0 = er[0], e1 = er[1];
    float r0 = BFL(e0.x) * w0[0]  + BFH(e0.x) * w0[1]
             + BFL(e0.y) * w0[2]  + BFH(e0.y) * w0[3]
             + BFL(e0.z) * w0[4]  + BFH(e0.z) * w0[5]
             + BFL(e0.w) * w0[6]  + BFH(e0.w) * w0[7]
             + BFL(e1.x) * w0[8]  + BFH(e1.x) * w0[9]
             + BFL(e1.y) * w0[10] + BFH(e1.y) * w0[11]
             + BFL(e1.z) * w0[12] + BFH(e1.z) * w0[13]
             + BFL(e1.w) * w0[14];
    float r1 = BFL(e0.x) * w1[0]  + BFH(e0.x) * w1[1]
             + BFL(e0.y) * w1[2]  + BFH(e0.y) * w1[3]
             + BFL(e0.z) * w1[4]  + BFH(e0.z) * w1[5]
             + BFL(e0.w) * w1[6]  + BFH(e0.w) * w1[7]
             + BFL(e1.x) * w1[8]  + BFH(e1.x) * w1[9]
             + BFL(e1.y) * w1[10] + BFH(e1.y) * w1[11]
             + BFL(e1.z) * w1[12] + BFH(e1.z) * w1[13]
             + BFL(e1.w) * w1[14];
    float sgn = dj > 0 ? 1.f : (dj < 0 ? -1.f : 0.f);
    lg[u] = cacc + r0 + sgn * r1;
  }
  // full-row softmax across the wave (512 logits, 8/lane), in registers
  float m = lg[0];
  #pragma unroll
  for (int u = 1; u < 8; ++u) m = fmaxf(m, lg[u]);
  #pragma unroll
  for (int s = 1; s < 64; s <<= 1) m = fmaxf(m, __shfl_xor(m, s));
  float ssum = 0.f;
  #pragma unroll
  for (int u = 0; u < 8; ++u) { lg[u] = __expf(lg[u] - m); ssum += lg[u]; }
  #pragma unroll
  for (int s = 1; s < 64; s <<= 1) ssum += __shfl_xor(ssum, s);
  float invs = 1.0f / ssum;
  // PV: p in registers, v coalesced; butterfly-reduce 8 partial d-sums
  float* obrow = ob + (size_t)(b * NSEL + i) * HDD + h * DKD;
  #pragma unroll
  for (int dp = 0; dp < 4; ++dp) {
    float acc[8] = {0.f, 0.f, 0.f, 0.f, 0.f, 0.f, 0.f, 0.f};
    #pragma unroll
    for (int u = 0; u < 8; ++u) {
      uint4 vv = vb4[dp * 512 + u * 64 + ln];
      float p = lg[u];
      acc[0] += p * BFL(vv.x); acc[1] += p * BFH(vv.x);
      acc[2] += p * BFL(vv.y); acc[3] += p * BFH(vv.y);
      acc[4] += p * BFL(vv.z); acc[5] += p * BFH(vv.z);
      acc[6] += p * BFL(vv.w); acc[7] += p * BFH(vv.w);
    }
    #pragma unroll
    for (int s = 1; s < 64; s <<= 1) {
      #pragma unroll
      for (int t = 0; t < 8; ++t) acc[t] += __shfl_xor(acc[t], s);
    }
    int sel = ln & 7;
    float oval = acc[0];
    #pragma unroll
    for (int t = 1; t < 8; ++t) oval = (sel == t) ? acc[t] : oval;
    if (ln < 8) obrow[dp * 8 + ln] = oval * invs;
  }
}

// ---------------- K5: fused proj+residual+LN2+MLP+residual, 2 rows/block ----
// grid 512 -> 2 blocks/CU (was 1): latency hiding for the L2 weight streams.
__global__ __launch_bounds__(256) void mlp_kernel(
    const float* __restrict__ ob, const float* __restrict__ Wo,
    const float* __restrict__ bo,
    const float* __restrict__ ln_g, const float* __restrict__ ln_b,
    const float* __restrict__ W1, const float* __restrict__ b1,
    const float* __restrict__ W2, const float* __restrict__ b2,
    float* __restrict__ emb, int layer) {
  __shared__ float part[2][8][32];
  __shared__ float res[2][32];
  __shared__ float hln[2][32];
  __shared__ float a1s[2][MLPD];
  int row0 = blockIdx.x * 2;
  int tid = threadIdx.x;
  int c = tid & 31, seg = tid >> 5;
  const float* wo = Wo + (size_t)layer * HDD * CCH + c;
  float pacc[2] = {0.f, 0.f};
  #pragma unroll
  for (int k = 0; k < 16; ++k) {
    int kk = seg * 16 + k;
    float w = wo[kk * CCH];
    #pragma unroll
    for (int r = 0; r < 2; ++r)
      pacc[r] += ob[(size_t)(row0 + r) * HDD + kk] * w;
  }
  #pragma unroll
  for (int r = 0; r < 2; ++r) part[r][seg][c] = pacc[r];
  __syncthreads();
  if (tid < 64) {
    int r = tid >> 5, cc = tid & 31;
    float s = bo[layer * CCH + cc] + emb[(size_t)(row0 + r) * CCH + cc];
    #pragma unroll
    for (int sg = 0; sg < 8; ++sg) s += part[r][sg][cc];
    res[r][cc] = s;
  }
  __syncthreads();
  if (tid < 64) {
    int r = tid >> 5, cc = tid & 31;
    float mu = 0.f, s2 = 0.f;
    #pragma unroll
    for (int c2 = 0; c2 < 32; ++c2) { float v = res[r][c2]; mu += v; s2 += v * v; }
    mu *= (1.0f / 32.0f);
    float var = s2 * (1.0f / 32.0f) - mu * mu;
    float rstd = rsqrtf(var + 1e-5f);
    hln[r][cc] = (res[r][cc] - mu) * rstd * ln_g[layer * CCH + cc] + ln_b[layer * CCH + cc];
  }
  __syncthreads();
  const float* w1 = W1 + (size_t)layer * CCH * MLPD;
  float accA[2], accB[2];
  float bA = b1[layer * MLPD + tid], bB = b1[layer * MLPD + tid + 256];
  #pragma unroll
  for (int r = 0; r < 2; ++r) { accA[r] = bA; accB[r] = bB; }
  for (int c2 = 0; c2 < 32; ++c2) {
    float wa = w1[c2 * MLPD + tid];
    float wb2 = w1[c2 * MLPD + tid + 256];
    #pragma unroll
    for (int r = 0; r < 2; ++r) {
      float hv = hln[r][c2];
      accA[r] += hv * wa;
      accB[r] += hv * wb2;
    }
  }
  #pragma unroll
  for (int r = 0; r < 2; ++r) {
    a1s[r][tid]       = 0.5f * accA[r] * (1.0f + erff(accA[r] * 0.70710678118654752f));
    a1s[r][tid + 256] = 0.5f * accB[r] * (1.0f + erff(accB[r] * 0.70710678118654752f));
  }
  __syncthreads();
  const float* w2 = W2 + (size_t)layer * MLPD * CCH;
  float acc2[2] = {0.f, 0.f};
  #pragma unroll 4
  for (int mi = 0; mi < 64; ++mi) {
    int m = seg * 64 + mi;
    float w = w2[m * CCH + c];
    #pragma unroll
    for (int r = 0; r < 2; ++r) acc2[r] += a1s[r][m] * w;
  }
  __syncthreads();                    // part[] reuse
  #pragma unroll
  for (int r = 0; r < 2; ++r) part[r][seg][c] = acc2[r];
  __syncthreads();
  if (tid < 64) {
    int r = tid >> 5, cc = tid & 31;
    float s = b2[layer * CCH + cc] + res[r][cc];
    #pragma unroll
    for (int sg = 0; sg < 8; ++sg) s += part[r][sg][cc];
    emb[(size_t)(row0 + r) * CCH + cc] = s;
  }
}

// ---------------- K7: scatter back ------------------------------------------
__global__ void scatter_kernel(const float* __restrict__ emb, const int* __restrict__ idx,
                               float* __restrict__ out) {
  int t = blockIdx.x * 256 + threadIdx.x;
  if (t >= NBAT * NSEL * CCH) return;
  int c = t & 31;
  int i = (t >> 5) & 511;
  int b = t >> 14;
  out[((size_t)b * CCH + c) * SEQL + idx[b * NSEL + i]] = emb[t];
}

extern "C" void kernel_launch(void* const* d_in, const int* in_sizes, int n_in,
                              void* d_out, int out_size, void* d_ws, size_t ws_size,
                              hipStream_t stream) {
  (void)in_sizes; (void)n_in; (void)ws_size;
  const float* x_skip    = (const float*)d_in[0];
  const float* attention = (const float*)d_in[1];
  const float* ln1_g = (const float*)d_in[2];
  const float* ln1_b = (const float*)d_in[3];
  const float* Wq    = (const float*)d_in[4];
  const float* Wk    = (const float*)d_in[5];
  const float* Wv    = (const float*)d_in[6];
  const float* Wrel  = (const float*)d_in[7];
  const float* rcb   = (const float*)d_in[8];
  const float* rpb   = (const float*)d_in[9];
  const float* Wo    = (const float*)d_in[10];
  const float* bo    = (const float*)d_in[11];
  const float* ln2_g = (const float*)d_in[12];
  const float* ln2_b = (const float*)d_in[13];
  const float* W1    = (const float*)d_in[14];
  const float* b1    = (const float*)d_in[15];
  const float* W2    = (const float*)d_in[16];
  const float* b2    = (const float*)d_in[17];
  float* out = (float*)d_out;
  char* ws = (char*)d_ws;

  unsigned short* E   = (unsigned short*)(ws + 0);    // 1,440,000
  int*      idx   = (int*)(ws + 1441792);             // 4,096
  float*    emb   = (float*)(ws + 1445888);           // 131,072
  float*    qc    = (float*)(ws + 1576960);           // 524,288
  unsigned short* kbT = (unsigned short*)(ws + 2101248); // 262,144
  unsigned short* vT  = (unsigned short*)(ws + 2363392); // 262,144
  float*    wb    = (float*)(ws + 2625536);           // 524,288
  float*    ob    = (float*)(ws + 3149824);           // 524,288
  int*      hist1 = (int*)(ws + 3674112);             // 1,048,576
  int*      cnt   = (int*)(ws + 4722688);             // 16
  int*      thr16 = (int*)(ws + 4722704);             // 16
  unsigned long long* cand = (unsigned long long*)(ws + 4722720); // 65,536 -> ~4.79 MB

  hipMemsetAsync(d_out, 0, (size_t)out_size * sizeof(float), stream);
  hipMemsetAsync(ws + 3674112, 0, 1048576 + 16, stream);  // hist1 + cnt
  prep_kernel<<<ETB + 4 * TKB, 256, 0, stream>>>(attention, E, hist1);
  topk_thresh_kernel<<<4, 1024, 0, stream>>>(hist1, thr16);
  topk_collect_kernel<<<4 * TKB, 256, 0, stream>>>(attention, thr16, cand, cnt);
  topk_final_kernel<<<2, 1024, 0, stream>>>(cand, cnt, idx);
  gather_kernel<<<128, 256, 0, stream>>>(x_skip, idx, emb);
  for (int l = 0; l < 4; ++l) {
    qkv_kernel<<<1024, 128, 0, stream>>>(emb, ln1_g, ln1_b, Wq, Wk, Wv,
                                         Wrel, rcb, rpb, qc, kbT, vT, wb, l);
    attn_kernel<<<1024, 256, 0, stream>>>(qc, kbT, vT, wb, E, idx, ob);
    mlp_kernel<<<512, 256, 0, stream>>>(ob, Wo, bo, ln2_g, ln2_b,
                                        W1, b1, W2, b2, emb, l);
  }
  scatter_kernel<<<128, 256, 0, stream>>>(emb, idx, out);
}

// Round 10
// 356.890 us; speedup vs baseline: 1.1302x; 1.0027x over previous
//
#include <hip/hip_runtime.h>
#include <math.h>

#define SEQL   45000
#define NBAT   2
#define CCH    32
#define NSEL   512
#define NHEAD  4
#define DKD    32
#define HDD    128
#define MLPD   512
#define CDCAP  2048
#define TKB    32     // scan slices per (b,channel)
#define ETB    176    // etab blocks = ceil(45000/256)

// bf16 helpers: round-to-nearest-even pack, cheap unpack (<<16)
__device__ __forceinline__ unsigned short f2bf(float x) {
  unsigned u = __float_as_uint(x);
  u = (u + 0x7fffu + ((u >> 16) & 1u)) >> 16;
  return (unsigned short)u;
}
#define BFL(u) __uint_as_float((u) << 16)
#define BFH(u) __uint_as_float((u) & 0xffff0000u)

// ---------------- K0: etab build + high16 hist + d_out zero -----------------
// NOTE: cooperative mega-kernel attempts (R8/R9) never executed under this
// harness (hipLaunchCooperativeKernel + graph capture incompatibility) —
// multi-kernel structure restored; fusions below need no grid sync.
__global__ __launch_bounds__(256) void prep_kernel(const float* __restrict__ att,
                                                   unsigned short* __restrict__ E,
                                                   int* __restrict__ hist,
                                                   float* __restrict__ out) {
  // all blocks: grid-stride zero of d_out (harness re-poisons it to 0xAA)
  {
    int nthr = gridDim.x * 256;
    int gt = blockIdx.x * 256 + threadIdx.x;
    float4 z4 = make_float4(0.f, 0.f, 0.f, 0.f);
    float4* o4 = (float4*)out;
    for (int i = gt; i < NBAT * CCH * SEQL / 4; i += nthr) o4[i] = z4;
  }
  if (blockIdx.x < ETB) {
    int a = blockIdx.x * 256 + threadIdx.x;
    if (a >= SEQL) return;
    float ad = (float)a;
    float outv[16];
    float log2S = log2f((float)SEQL);
    #pragma unroll
    for (int k = 0; k < 5; ++k) {
      float hl = exp2f(3.0f + (float)k * (log2S - 3.0f) * 0.25f);
      outv[k] = exp2f(-ad / hl);
    }
    const int cw[5] = {1, 3, 7, 15, 31};
    #pragma unroll
    for (int k = 0; k < 5; ++k) outv[5 + k] = (a < cw[k]) ? 1.0f : 0.0f;
    float pmax = 0.0f;
    float pk[5];
    #pragma unroll
    for (int k = 0; k < 5; ++k) {
      float mean = 9000.0f * (float)(k + 1);
      float sd = 4500.0f;
      float cc = (mean / sd) * (mean / sd);      // 4,16,36,64,100
      float rr = mean / (sd * sd);
      float logz = lgammaf(cc) - cc * logf(rr);
      float pp;
      if (a == 0) pp = 1e-8f;                    // xlogy -> -inf -> exp = 0
      else pp = expf((cc - 1.0f) * logf(ad) - rr * ad - logz) + 1e-8f;
      pk[k] = pp;
      float mstar = (cc - 1.0f) / rr;            // 6750..44550, interior mode
      float m0 = floorf(mstar), m1 = m0 + 1.0f;
      if (m1 > (float)(SEQL - 1)) m1 = (float)(SEQL - 1);
      float p0 = expf((cc - 1.0f) * logf(m0) - rr * m0 - logz) + 1e-8f;
      float p1 = expf((cc - 1.0f) * logf(m1) - rr * m1 - logz) + 1e-8f;
      pmax = fmaxf(pmax, fmaxf(p0, p1));
    }
    #pragma unroll
    for (int k = 0; k < 5; ++k) outv[10 + k] = pk[k] / pmax;
    outv[15] = 0.0f;
    uint4 o0, o1;
    o0.x = (unsigned)f2bf(outv[0])  | ((unsigned)f2bf(outv[1])  << 16);
    o0.y = (unsigned)f2bf(outv[2])  | ((unsigned)f2bf(outv[3])  << 16);
    o0.z = (unsigned)f2bf(outv[4])  | ((unsigned)f2bf(outv[5])  << 16);
    o0.w = (unsigned)f2bf(outv[6])  | ((unsigned)f2bf(outv[7])  << 16);
    o1.x = (unsigned)f2bf(outv[8])  | ((unsigned)f2bf(outv[9])  << 16);
    o1.y = (unsigned)f2bf(outv[10]) | ((unsigned)f2bf(outv[11]) << 16);
    o1.z = (unsigned)f2bf(outv[12]) | ((unsigned)f2bf(outv[13]) << 16);
    o1.w = (unsigned)f2bf(outv[14]);
    uint4* E4 = (uint4*)(E + (size_t)a * 16);
    E4[0] = o0;
    E4[1] = o1;
  } else {
    int bid = blockIdx.x - ETB;
    int ch4 = bid / TKB;
    int blk = bid % TKB;
    int b = ch4 >> 1, ch = ch4 & 1;
    const float* row = att + ((size_t)b * 3 + 1 + ch) * SEQL;
    int* h = hist + (size_t)ch4 * 65536;
    int per = (SEQL + TKB - 1) / TKB;
    int lo = blk * per;
    int hi = lo + per; if (hi > SEQL) hi = SEQL;
    for (int i = lo + threadIdx.x; i < hi; i += 256)
      atomicAdd(&h[__float_as_uint(row[i]) >> 16], 1);  // vals>=0 -> monotone
  }
}

// ---------------- K1: collect w/ inline threshold ---------------------------
// Every block redundantly computes T16 from the (read-only) hist via a
// 2-stage 256-thread suffix scan, then collects its slice's candidates.
__global__ __launch_bounds__(256) void topk_collect_kernel(
    const float* __restrict__ att, const int* __restrict__ hist,
    unsigned long long* __restrict__ cand, int* __restrict__ cnt) {
  __shared__ int s_scan[256];
  __shared__ int s_aux[2];
  int tid = threadIdx.x;
  int ch4 = blockIdx.x / TKB;
  int blk = blockIdx.x % TKB;
  const int* h = hist + (size_t)ch4 * 65536;
  // stage 1: 256-bin chunk sums, suffix scan, find crossing chunk
  {
    int base = tid * 256;
    int sum = 0;
    for (int i = 0; i < 64; ++i) {
      int4 v = ((const int4*)(h + base))[i];
      sum += v.x + v.y + v.z + v.w;
    }
    s_scan[tid] = sum;
  }
  __syncthreads();
  for (int d = 1; d < 256; d <<= 1) {
    int v = s_scan[tid] + ((tid + d < 256) ? s_scan[tid + d] : 0);
    __syncthreads();
    s_scan[tid] = v;
    __syncthreads();
  }
  {
    int sufEx = (tid == 255) ? 0 : s_scan[tid + 1];
    if (s_scan[tid] >= 256 && sufEx < 256) { s_aux[0] = tid; s_aux[1] = 256 - sufEx; }
  }
  __syncthreads();
  int chunk = s_aux[0], want = s_aux[1];
  s_scan[tid] = h[chunk * 256 + tid];
  __syncthreads();
  for (int d = 1; d < 256; d <<= 1) {
    int v = s_scan[tid] + ((tid + d < 256) ? s_scan[tid + d] : 0);
    __syncthreads();
    s_scan[tid] = v;
    __syncthreads();
  }
  {
    int sufEx2 = (tid == 255) ? 0 : s_scan[tid + 1];
    if (s_scan[tid] >= want && sufEx2 < want) s_aux[0] = chunk * 256 + tid;
  }
  __syncthreads();
  unsigned T16 = (unsigned)s_aux[0];
  // collect this slice
  int b = ch4 >> 1, ch = ch4 & 1;
  const float* row = att + ((size_t)b * 3 + 1 + ch) * SEQL;
  int per = (SEQL + TKB - 1) / TKB;
  int lo = blk * per;
  int hi = lo + per; if (hi > SEQL) hi = SEQL;
  for (int i = lo + tid; i < hi; i += 256) {
    unsigned key = __float_as_uint(row[i]);
    if ((key >> 16) >= T16) {
      int p = atomicAdd(&cnt[ch4], 1);
      if (p < CDCAP)
        cand[(size_t)ch4 * CDCAP + p] =
            ((unsigned long long)key << 32) | (unsigned)(~(unsigned)i);
    }
  }
}

// ---------------- K2: per batch — desc sort both channels, merge, asc sort --
__global__ __launch_bounds__(1024) void topk_final_kernel(
    const unsigned long long* __restrict__ cand, const int* __restrict__ cnt,
    int* __restrict__ idx) {
  __shared__ unsigned long long sc[CDCAP];
  __shared__ int m[512];
  int b = blockIdx.x, t = threadIdx.x;
  for (int ch = 0; ch < 2; ++ch) {
    int ch4 = b * 2 + ch;
    int n = cnt[ch4]; if (n > CDCAP) n = CDCAP;   // >=256 by construction
    int P = 256;
    while (P < n) P <<= 1;                        // typical 512
    for (int i = t; i < P; i += 1024)
      sc[i] = (i < n) ? cand[(size_t)ch4 * CDCAP + i] : 0ull;  // 0 sorts last
    __syncthreads();
    for (int k = 2; k <= P; k <<= 1) {
      for (int j = k >> 1; j > 0; j >>= 1) {
        for (int i = t; i < P; i += 1024) {
          int ixj = i ^ j;
          if (ixj > i) {
            unsigned long long va = sc[i], vb2 = sc[ixj];
            bool up = ((i & k) == 0);
            if ((va < vb2) == up) { sc[i] = vb2; sc[ixj] = va; }
          }
        }
        __syncthreads();
      }
    }
    if (t < 256)
      m[ch * 256 + t] = (int)~(unsigned)(sc[t] & 0xFFFFFFFFull);
    __syncthreads();
  }
  for (int k = 2; k <= 512; k <<= 1) {
    for (int j = k >> 1; j > 0; j >>= 1) {
      if (t < 512) {
        int ixj = t ^ j;
        if (ixj > t) {
          int va = m[t], vb2 = m[ixj];
          bool up = ((t & k) == 0);
          if ((va > vb2) == up) { m[t] = vb2; m[ixj] = va; }
        }
      }
      __syncthreads();
    }
  }
  if (t < 512) idx[b * 512 + t] = m[t];
}

// ---------------- K3: fused gather + LN1 + QKV layer 0 ----------------------
// kbT/vT layout (bf16): [((b*4+h)*4+dpack)*4096 + i*8 + (d&7)]
__global__ __launch_bounds__(128) void gqkv0_kernel(
    const float* __restrict__ x, const int* __restrict__ idx,
    const float* __restrict__ ln_g, const float* __restrict__ ln_b,
    const float* __restrict__ Wq, const float* __restrict__ Wk,
    const float* __restrict__ Wv, const float* __restrict__ Wrel,
    const float* __restrict__ rcb, const float* __restrict__ rpb,
    float* __restrict__ emb, float* __restrict__ qc,
    unsigned short* __restrict__ kbT, unsigned short* __restrict__ vT,
    float* __restrict__ wb) {
  __shared__ float qs[128];
  const int l = 0;
  int hd = threadIdx.x;        // 0..127
  int hh = hd >> 5, d = hd & 31;
  int row = blockIdx.x;        // b*512 + i
  int b = row >> 9, ii = row & 511;
  int li = idx[b * NSEL + ii];
  float h[32];
  float mu = 0.f;
  #pragma unroll
  for (int c = 0; c < 32; ++c) {
    h[c] = x[((size_t)b * CCH + c) * SEQL + li];
    mu += h[c];
  }
  if (hd < 32) emb[(size_t)row * CCH + hd] = h[hd];
  mu *= (1.0f / 32.0f);
  float var = 0.f;
  #pragma unroll
  for (int c = 0; c < 32; ++c) { float dd0 = h[c] - mu; var += dd0 * dd0; }
  var *= (1.0f / 32.0f);
  float rstd = rsqrtf(var + 1e-5f);
  const float* g = ln_g + l * CCH;
  const float* bb = ln_b + l * CCH;
  #pragma unroll
  for (int c = 0; c < 32; ++c) h[c] = (h[c] - mu) * rstd * g[c] + bb[c];
  const float* wq = Wq + (size_t)l * CCH * HDD + hd;
  const float* wk = Wk + (size_t)l * CCH * HDD + hd;
  const float* wv = Wv + (size_t)l * CCH * HDD + hd;
  float q = 0.f, kk = 0.f, vv = 0.f;
  #pragma unroll
  for (int c = 0; c < 32; ++c) {
    q += h[c] * wq[c * HDD];
    kk += h[c] * wk[c * HDD];
    vv += h[c] * wv[c * HDD];
  }
  q *= 0.17677669529663687f;   // DK^-0.5
  qs[hd] = q;
  qc[(size_t)row * HDD + hd] = q + rcb[(l * NHEAD + hh) * DKD + d];
  size_t tpos = ((size_t)(b * 4 + hh) * 4 + (d >> 3)) * 4096 + (size_t)ii * 8 + (d & 7);
  kbT[tpos] = f2bf(kk);
  vT[tpos]  = f2bf(vv);
  __syncthreads();
  if (hd < 120) {
    int h2 = hd / 30, f = hd % 30;
    const float* wr = Wrel + ((size_t)l * 30 + f) * HDD + h2 * DKD;
    const float* rp = rpb + (l * NHEAD + h2) * DKD;
    const float* qsh = qs + h2 * DKD;
    float acc = 0.f;
    #pragma unroll
    for (int dd = 0; dd < 32; ++dd) acc += (qsh[dd] + rp[dd]) * wr[dd];
    wb[((size_t)row * NHEAD + h2) * 32 + f] = acc;   // padded stride 32
  }
}

// ---------------- K4: attention (content + rel + softmax + PV) --------------
// 1024 blocks (b, h, 4 i-rows), 4 waves, 1 row/wave. All-coalesced:
// k AND v via transposed bf16 layout; softmax p stays in registers.
__global__ __launch_bounds__(256, 4) void attn_kernel(
    const float* __restrict__ qc, const unsigned short* __restrict__ kbT,
    const unsigned short* __restrict__ vT, const float* __restrict__ wbuf,
    const unsigned short* __restrict__ E, const int* __restrict__ idx,
    float* __restrict__ ob) {
  __shared__ int idxl[512];
  int bid = blockIdx.x;
  int b = bid >> 9;
  int h = (bid >> 7) & 3;
  int i0 = (bid & 127) * 4;
  int tid = threadIdx.x;
  int wv = tid >> 6, ln = tid & 63;
  for (int i = tid; i < 512; i += 256) idxl[i] = idx[b * NSEL + i];
  __syncthreads();
  int i = i0 + wv;
  const float* qrow = qc + (size_t)(b * NSEL + i) * HDD + h * DKD;
  float q[32];
  #pragma unroll
  for (int d4 = 0; d4 < 8; ++d4) {
    float4 qv = *(const float4*)(qrow + d4 * 4);
    q[d4 * 4 + 0] = qv.x; q[d4 * 4 + 1] = qv.y;
    q[d4 * 4 + 2] = qv.z; q[d4 * 4 + 3] = qv.w;
  }
  const float* wrow = wbuf + ((size_t)(b * NSEL + i) * NHEAD + h) * 32;
  float w0[15], w1[15];
  #pragma unroll
  for (int f = 0; f < 15; ++f) { w0[f] = wrow[f]; w1[f] = wrow[15 + f]; }
  int ii = idxl[i];
  const uint4* kb4 = (const uint4*)kbT + (size_t)(b * 4 + h) * 4 * 512;
  const uint4* vb4 = (const uint4*)vT + (size_t)(b * 4 + h) * 4 * 512;
  float lg[8];
  #pragma unroll
  for (int u = 0; u < 8; ++u) {
    int j = u * 64 + ln;
    int dj = ii - idxl[j];
    float cacc = 0.f;
    #pragma unroll
    for (int dp = 0; dp < 4; ++dp) {
      uint4 kv = kb4[dp * 512 + j];
      cacc += q[dp * 8 + 0] * BFL(kv.x) + q[dp * 8 + 1] * BFH(kv.x)
            + q[dp * 8 + 2] * BFL(kv.y) + q[dp * 8 + 3] * BFH(kv.y)
            + q[dp * 8 + 4] * BFL(kv.z) + q[dp * 8 + 5] * BFH(kv.z)
            + q[dp * 8 + 6] * BFL(kv.w) + q[dp * 8 + 7] * BFH(kv.w);
    }
    int a = dj < 0 ? -dj : dj;
    const uint4* er = (const uint4*)(E + (size_t)a * 16);
    uint4 e0 = er[0], e1 = er[1];
    float r0 = BFL(e0.x) * w0[0]  + BFH(e0.x) * w0[1]
             + BFL(e0.y) * w0[2]  + BFH(e0.y) * w0[3]
             + BFL(e0.z) * w0[4]  + BFH(e0.z) * w0[5]
             + BFL(e0.w) * w0[6]  + BFH(e0.w) * w0[7]
             + BFL(e1.x) * w0[8]  + BFH(e1.x) * w0[9]
             + BFL(e1.y) * w0[10] + BFH(e1.y) * w0[11]
             + BFL(e1.z) * w0[12] + BFH(e1.z) * w0[13]
             + BFL(e1.w) * w0[14];
    float r1 = BFL(e0.x) * w1[0]  + BFH(e0.x) * w1[1]
             + BFL(e0.y) * w1[2]  + BFH(e0.y) * w1[3]
             + BFL(e0.z) * w1[4]  + BFH(e0.z) * w1[5]
             + BFL(e0.w) * w1[6]  + BFH(e0.w) * w1[7]
             + BFL(e1.x) * w1[8]  + BFH(e1.x) * w1[9]
             + BFL(e1.y) * w1[10] + BFH(e1.y) * w1[11]
             + BFL(e1.z) * w1[12] + BFH(e1.z) * w1[13]
             + BFL(e1.w) * w1[14];
    float sgn = dj > 0 ? 1.f : (dj < 0 ? -1.f : 0.f);
    lg[u] = cacc + r0 + sgn * r1;
  }
  // full-row softmax across the wave (512 logits, 8/lane), in registers
  float m = lg[0];
  #pragma unroll
  for (int u = 1; u < 8; ++u) m = fmaxf(m, lg[u]);
  #pragma unroll
  for (int s = 1; s < 64; s <<= 1) m = fmaxf(m, __shfl_xor(m, s));
  float ssum = 0.f;
  #pragma unroll
  for (int u = 0; u < 8; ++u) { lg[u] = __expf(lg[u] - m); ssum += lg[u]; }
  #pragma unroll
  for (int s = 1; s < 64; s <<= 1) ssum += __shfl_xor(ssum, s);
  float invs = 1.0f / ssum;
  // PV: p in registers, v coalesced; butterfly-reduce 8 partial d-sums
  float* obrow = ob + (size_t)(b * NSEL + i) * HDD + h * DKD;
  #pragma unroll
  for (int dp = 0; dp < 4; ++dp) {
    float acc[8] = {0.f, 0.f, 0.f, 0.f, 0.f, 0.f, 0.f, 0.f};
    #pragma unroll
    for (int u = 0; u < 8; ++u) {
      uint4 vv = vb4[dp * 512 + u * 64 + ln];
      float p = lg[u];
      acc[0] += p * BFL(vv.x); acc[1] += p * BFH(vv.x);
      acc[2] += p * BFL(vv.y); acc[3] += p * BFH(vv.y);
      acc[4] += p * BFL(vv.z); acc[5] += p * BFH(vv.z);
      acc[6] += p * BFL(vv.w); acc[7] += p * BFH(vv.w);
    }
    #pragma unroll
    for (int s = 1; s < 64; s <<= 1) {
      #pragma unroll
      for (int t = 0; t < 8; ++t) acc[t] += __shfl_xor(acc[t], s);
    }
    int sel = ln & 7;
    float oval = acc[0];
    #pragma unroll
    for (int t = 1; t < 8; ++t) oval = (sel == t) ? acc[t] : oval;
    if (ln < 8) obrow[dp * 8 + ln] = oval * invs;
  }
}

// ---------------- K5: fused proj+res+LN2+MLP+res (2 rows) + qkv(l+1)/scatter
__global__ __launch_bounds__(256) void mlpqkv_kernel(
    const float* __restrict__ ob, const float* __restrict__ Wo,
    const float* __restrict__ bo,
    const float* __restrict__ ln2_g, const float* __restrict__ ln2_b,
    const float* __restrict__ W1, const float* __restrict__ b1,
    const float* __restrict__ W2, const float* __restrict__ b2,
    const float* __restrict__ ln1_g, const float* __restrict__ ln1_b,
    const float* __restrict__ Wq, const float* __restrict__ Wk,
    const float* __restrict__ Wv, const float* __restrict__ Wrel,
    const float* __restrict__ rcb, const float* __restrict__ rpb,
    const int* __restrict__ idx, float* __restrict__ emb,
    float* __restrict__ qc, unsigned short* __restrict__ kbT,
    unsigned short* __restrict__ vT, float* __restrict__ wb,
    float* __restrict__ out, int layer) {
  __shared__ float part[2][8][32];
  __shared__ float res[2][32];
  __shared__ float hln[2][32];
  __shared__ float fin[2][32];
  __shared__ float a1s[2][MLPD];
  __shared__ float qs[2][128];
  int row0 = blockIdx.x * 2;
  int tid = threadIdx.x;
  int c = tid & 31, seg = tid >> 5;
  const float* wo = Wo + (size_t)layer * HDD * CCH + c;
  float pacc[2] = {0.f, 0.f};
  #pragma unroll
  for (int k = 0; k < 16; ++k) {
    int kk = seg * 16 + k;
    float w = wo[kk * CCH];
    #pragma unroll
    for (int r = 0; r < 2; ++r)
      pacc[r] += ob[(size_t)(row0 + r) * HDD + kk] * w;
  }
  #pragma unroll
  for (int r = 0; r < 2; ++r) part[r][seg][c] = pacc[r];
  __syncthreads();
  if (tid < 64) {
    int r = tid >> 5, cc = tid & 31;
    float s = bo[layer * CCH + cc] + emb[(size_t)(row0 + r) * CCH + cc];
    #pragma unroll
    for (int sg = 0; sg < 8; ++sg) s += part[r][sg][cc];
    res[r][cc] = s;
  }
  __syncthreads();
  if (tid < 64) {
    int r = tid >> 5, cc = tid & 31;
    float mu = 0.f, s2 = 0.f;
    #pragma unroll
    for (int c2 = 0; c2 < 32; ++c2) { float v = res[r][c2]; mu += v; s2 += v * v; }
    mu *= (1.0f / 32.0f);
    float var = s2 * (1.0f / 32.0f) - mu * mu;
    float rstd = rsqrtf(var + 1e-5f);
    hln[r][cc] = (res[r][cc] - mu) * rstd * ln2_g[layer * CCH + cc] + ln2_b[layer * CCH + cc];
  }
  __syncthreads();
  const float* w1 = W1 + (size_t)layer * CCH * MLPD;
  float accA[2], accB[2];
  float bA = b1[layer * MLPD + tid], bB = b1[layer * MLPD + tid + 256];
  #pragma unroll
  for (int r = 0; r < 2; ++r) { accA[r] = bA; accB[r] = bB; }
  for (int c2 = 0; c2 < 32; ++c2) {
    float wa = w1[c2 * MLPD + tid];
    float wb2 = w1[c2 * MLPD + tid + 256];
    #pragma unroll
    for (int r = 0; r < 2; ++r) {
      float hv = hln[r][c2];
      accA[r] += hv * wa;
      accB[r] += hv * wb2;
    }
  }
  #pragma unroll
  for (int r = 0; r < 2; ++r) {
    a1s[r][tid]       = 0.5f * accA[r] * (1.0f + erff(accA[r] * 0.70710678118654752f));
    a1s[r][tid + 256] = 0.5f * accB[r] * (1.0f + erff(accB[r] * 0.70710678118654752f));
  }
  __syncthreads();
  const float* w2 = W2 + (size_t)layer * MLPD * CCH;
  float acc2[2] = {0.f, 0.f};
  #pragma unroll 4
  for (int mi = 0; mi < 64; ++mi) {
    int m = seg * 64 + mi;
    float w = w2[m * CCH + c];
    #pragma unroll
    for (int r = 0; r < 2; ++r) acc2[r] += a1s[r][m] * w;
  }
  __syncthreads();                    // part[] reuse
  #pragma unroll
  for (int r = 0; r < 2; ++r) part[r][seg][c] = acc2[r];
  __syncthreads();
  if (tid < 64) {
    int r = tid >> 5, cc = tid & 31;
    float s = b2[layer * CCH + cc] + res[r][cc];
    #pragma unroll
    for (int sg = 0; sg < 8; ++sg) s += part[r][sg][cc];
    fin[r][cc] = s;
    if (layer < 3) emb[(size_t)(row0 + r) * CCH + cc] = s;
  }
  __syncthreads();
  if (layer == 3) {
    // final scatter to d_out
    if (tid < 64) {
      int r = tid >> 5, cc = tid & 31;
      int row = row0 + r;
      int b = row >> 9, ii = row & 511;
      int li = idx[b * NSEL + ii];
      out[((size_t)b * CCH + cc) * SEQL + li] = fin[r][cc];
    }
    return;
  }
  // fused qkv for layer+1 on the same 2 rows (no grid dependency)
  const int l1 = layer + 1;
  bool act = tid < 128;
  int hd = tid & 127;
  int hh = hd >> 5, d = hd & 31;
  #pragma unroll
  for (int r = 0; r < 2; ++r) {
    int row = row0 + r;
    int b = row >> 9, ii = row & 511;
    if (act) {
      float h[32];
      float mu = 0.f;
      #pragma unroll
      for (int c2 = 0; c2 < 32; ++c2) { h[c2] = fin[r][c2]; mu += h[c2]; }
      mu *= (1.0f / 32.0f);
      float var = 0.f;
      #pragma unroll
      for (int c2 = 0; c2 < 32; ++c2) { float dd = h[c2] - mu; var += dd * dd; }
      var *= (1.0f / 32.0f);
      float rstd = rsqrtf(var + 1e-5f);
      const float* g = ln1_g + l1 * CCH;
      const float* bb = ln1_b + l1 * CCH;
      #pragma unroll
      for (int c2 = 0; c2 < 32; ++c2) h[c2] = (h[c2] - mu) * rstd * g[c2] + bb[c2];
      const float* wq = Wq + (size_t)l1 * CCH * HDD + hd;
      const float* wk = Wk + (size_t)l1 * CCH * HDD + hd;
      const float* wv = Wv + (size_t)l1 * CCH * HDD + hd;
      float q = 0.f, kk = 0.f, vv = 0.f;
      #pragma unroll
      for (int c2 = 0; c2 < 32; ++c2) {
        q += h[c2] * wq[c2 * HDD];
        kk += h[c2] * wk[c2 * HDD];
        vv += h[c2] * wv[c2 * HDD];
      }
      q *= 0.17677669529663687f;
      qs[r][hd] = q;
      qc[(size_t)row * HDD + hd] = q + rcb[(l1 * NHEAD + hh) * DKD + d];
      size_t tpos = ((size_t)(b * 4 + hh) * 4 + (d >> 3)) * 4096 + (size_t)ii * 8 + (d & 7);
      kbT[tpos] = f2bf(kk);
      vT[tpos]  = f2bf(vv);
    }
  }
  __syncthreads();
  if (act && hd < 120) {
    int h2 = hd / 30, f = hd % 30;
    const float* rp = rpb + (l1 * NHEAD + h2) * DKD;
    const float* wr = Wrel + ((size_t)l1 * 30 + f) * HDD + h2 * DKD;
    #pragma unroll
    for (int r = 0; r < 2; ++r) {
      int row = row0 + r;
      const float* qsh = qs[r] + h2 * DKD;
      float acc = 0.f;
      #pragma unroll
      for (int dd = 0; dd < 32; ++dd) acc += (qsh[dd] + rp[dd]) * wr[dd];
      wb[((size_t)row * NHEAD + h2) * 32 + f] = acc;
    }
  }
}

extern "C" void kernel_launch(void* const* d_in, const int* in_sizes, int n_in,
                              void* d_out, int out_size, void* d_ws, size_t ws_size,
                              hipStream_t stream) {
  (void)in_sizes; (void)n_in; (void)ws_size; (void)out_size;
  const float* x_skip    = (const float*)d_in[0];
  const float* attention = (const float*)d_in[1];
  const float* ln1_g = (const float*)d_in[2];
  const float* ln1_b = (const float*)d_in[3];
  const float* Wq    = (const float*)d_in[4];
  const float* Wk    = (const float*)d_in[5];
  const float* Wv    = (const float*)d_in[6];
  const float* Wrel  = (const float*)d_in[7];
  const float* rcb   = (const float*)d_in[8];
  const float* rpb   = (const float*)d_in[9];
  const float* Wo    = (const float*)d_in[10];
  const float* bo    = (const float*)d_in[11];
  const float* ln2_g = (const float*)d_in[12];
  const float* ln2_b = (const float*)d_in[13];
  const float* W1    = (const float*)d_in[14];
  const float* b1    = (const float*)d_in[15];
  const float* W2    = (const float*)d_in[16];
  const float* b2    = (const float*)d_in[17];
  float* out = (float*)d_out;
  char* ws = (char*)d_ws;

  unsigned short* E   = (unsigned short*)(ws + 0);    // 1,440,000
  int*      idx   = (int*)(ws + 1441792);             // 4,096
  float*    emb   = (float*)(ws + 1445888);           // 131,072
  float*    qc    = (float*)(ws + 1576960);           // 524,288
  unsigned short* kbT = (unsigned short*)(ws + 2101248); // 262,144
  unsigned short* vT  = (unsigned short*)(ws + 2363392); // 262,144
  float*    wb    = (float*)(ws + 2625536);           // 524,288
  float*    ob    = (float*)(ws + 3149824);           // 524,288
  int*      hist  = (int*)(ws + 3674112);             // 1,048,576
  int*      cnt   = (int*)(ws + 4722688);             // 16
  unsigned long long* cand = (unsigned long long*)(ws + 4722720); // 65,536

  hipMemsetAsync(ws + 3674112, 0, 1048576 + 32, stream);   // hist + cnt
  prep_kernel<<<ETB + 4 * TKB, 256, 0, stream>>>(attention, E, hist, out);
  topk_collect_kernel<<<4 * TKB, 256, 0, stream>>>(attention, hist, cand, cnt);
  topk_final_kernel<<<2, 1024, 0, stream>>>(cand, cnt, idx);
  gqkv0_kernel<<<1024, 128, 0, stream>>>(x_skip, idx, ln1_g, ln1_b, Wq, Wk, Wv,
                                         Wrel, rcb, rpb, emb, qc, kbT, vT, wb);
  for (int l = 0; l < 4; ++l) {
    attn_kernel<<<1024, 256, 0, stream>>>(qc, kbT, vT, wb, E, idx, ob);
    mlpqkv_kernel<<<512, 256, 0, stream>>>(ob, Wo, bo, ln2_g, ln2_b, W1, b1,
                                           W2, b2, ln1_g, ln1_b, Wq, Wk, Wv,
                                           Wrel, rcb, rpb, idx, emb, qc, kbT,
                                           vT, wb, out, l);
  }
}

// Round 11
// 343.223 us; speedup vs baseline: 1.1752x; 1.0398x over previous
//
#include <hip/hip_runtime.h>
#include <math.h>

#define SEQL   45000
#define NBAT   2
#define CCH    32
#define NSEL   512
#define NHEAD  4
#define DKD    32
#define HDD    128
#define MLPD   512
#define CDCAP  2048
#define TKB    32     // scan slices per (b,channel)
#define ETB    176    // etab blocks = ceil(45000/256)

// bf16 helpers: round-to-nearest-even pack, cheap unpack (<<16)
__device__ __forceinline__ unsigned short f2bf(float x) {
  unsigned u = __float_as_uint(x);
  u = (u + 0x7fffu + ((u >> 16) & 1u)) >> 16;
  return (unsigned short)u;
}
#define BFL(u) __uint_as_float((u) << 16)
#define BFH(u) __uint_as_float((u) & 0xffff0000u)
#define U8F(w, s) ((float)(((w) >> (s)) & 0xffu))

// ---------------- K0: etab build (u8) + high16 hist + d_out zero ------------
// E features are all in [0,1] by construction -> u8 quantization (err <= 1/510)
// packs a row into ONE uint4: halves the per-pair gather count in attn.
__global__ __launch_bounds__(256) void prep_kernel(const float* __restrict__ att,
                                                   unsigned char* __restrict__ E,
                                                   int* __restrict__ hist,
                                                   float* __restrict__ out) {
  // all blocks: grid-stride zero of d_out (harness re-poisons it to 0xAA)
  {
    int nthr = gridDim.x * 256;
    int gt = blockIdx.x * 256 + threadIdx.x;
    float4 z4 = make_float4(0.f, 0.f, 0.f, 0.f);
    float4* o4 = (float4*)out;
    for (int i = gt; i < NBAT * CCH * SEQL / 4; i += nthr) o4[i] = z4;
  }
  if (blockIdx.x < ETB) {
    int a = blockIdx.x * 256 + threadIdx.x;
    if (a >= SEQL) return;
    float ad = (float)a;
    float outv[16];
    float log2S = log2f((float)SEQL);
    #pragma unroll
    for (int k = 0; k < 5; ++k) {
      float hl = exp2f(3.0f + (float)k * (log2S - 3.0f) * 0.25f);
      outv[k] = exp2f(-ad / hl);
    }
    const int cw[5] = {1, 3, 7, 15, 31};
    #pragma unroll
    for (int k = 0; k < 5; ++k) outv[5 + k] = (a < cw[k]) ? 1.0f : 0.0f;
    float pmax = 0.0f;
    float pk[5];
    #pragma unroll
    for (int k = 0; k < 5; ++k) {
      float mean = 9000.0f * (float)(k + 1);
      float sd = 4500.0f;
      float cc = (mean / sd) * (mean / sd);      // 4,16,36,64,100
      float rr = mean / (sd * sd);
      float logz = lgammaf(cc) - cc * logf(rr);
      float pp;
      if (a == 0) pp = 1e-8f;                    // xlogy -> -inf -> exp = 0
      else pp = expf((cc - 1.0f) * logf(ad) - rr * ad - logz) + 1e-8f;
      pk[k] = pp;
      float mstar = (cc - 1.0f) / rr;            // 6750..44550, interior mode
      float m0 = floorf(mstar), m1 = m0 + 1.0f;
      if (m1 > (float)(SEQL - 1)) m1 = (float)(SEQL - 1);
      float p0 = expf((cc - 1.0f) * logf(m0) - rr * m0 - logz) + 1e-8f;
      float p1 = expf((cc - 1.0f) * logf(m1) - rr * m1 - logz) + 1e-8f;
      pmax = fmaxf(pmax, fmaxf(p0, p1));
    }
    #pragma unroll
    for (int k = 0; k < 5; ++k) outv[10 + k] = pk[k] / pmax;
    outv[15] = 0.0f;
    unsigned by[16];
    #pragma unroll
    for (int k = 0; k < 15; ++k)
      by[k] = (unsigned)(fminf(fmaxf(outv[k], 0.f), 1.f) * 255.f + 0.5f);
    by[15] = 0u;
    uint4 o;
    o.x = by[0]  | (by[1]  << 8) | (by[2]  << 16) | (by[3]  << 24);
    o.y = by[4]  | (by[5]  << 8) | (by[6]  << 16) | (by[7]  << 24);
    o.z = by[8]  | (by[9]  << 8) | (by[10] << 16) | (by[11] << 24);
    o.w = by[12] | (by[13] << 8) | (by[14] << 16);
    *(uint4*)(E + (size_t)a * 16) = o;
  } else {
    int bid = blockIdx.x - ETB;
    int ch4 = bid / TKB;
    int blk = bid % TKB;
    int b = ch4 >> 1, ch = ch4 & 1;
    const float* row = att + ((size_t)b * 3 + 1 + ch) * SEQL;
    int* h = hist + (size_t)ch4 * 65536;
    int per = (SEQL + TKB - 1) / TKB;
    int lo = blk * per;
    int hi = lo + per; if (hi > SEQL) hi = SEQL;
    for (int i = lo + threadIdx.x; i < hi; i += 256)
      atomicAdd(&h[__float_as_uint(row[i]) >> 16], 1);  // vals>=0 -> monotone
  }
}

// ---------------- K1: collect w/ inline threshold ---------------------------
__global__ __launch_bounds__(256) void topk_collect_kernel(
    const float* __restrict__ att, const int* __restrict__ hist,
    unsigned long long* __restrict__ cand, int* __restrict__ cnt) {
  __shared__ int s_scan[256];
  __shared__ int s_aux[2];
  int tid = threadIdx.x;
  int ch4 = blockIdx.x / TKB;
  int blk = blockIdx.x % TKB;
  const int* h = hist + (size_t)ch4 * 65536;
  {
    int base = tid * 256;
    int sum = 0;
    for (int i = 0; i < 64; ++i) {
      int4 v = ((const int4*)(h + base))[i];
      sum += v.x + v.y + v.z + v.w;
    }
    s_scan[tid] = sum;
  }
  __syncthreads();
  for (int d = 1; d < 256; d <<= 1) {
    int v = s_scan[tid] + ((tid + d < 256) ? s_scan[tid + d] : 0);
    __syncthreads();
    s_scan[tid] = v;
    __syncthreads();
  }
  {
    int sufEx = (tid == 255) ? 0 : s_scan[tid + 1];
    if (s_scan[tid] >= 256 && sufEx < 256) { s_aux[0] = tid; s_aux[1] = 256 - sufEx; }
  }
  __syncthreads();
  int chunk = s_aux[0], want = s_aux[1];
  s_scan[tid] = h[chunk * 256 + tid];
  __syncthreads();
  for (int d = 1; d < 256; d <<= 1) {
    int v = s_scan[tid] + ((tid + d < 256) ? s_scan[tid + d] : 0);
    __syncthreads();
    s_scan[tid] = v;
    __syncthreads();
  }
  {
    int sufEx2 = (tid == 255) ? 0 : s_scan[tid + 1];
    if (s_scan[tid] >= want && sufEx2 < want) s_aux[0] = chunk * 256 + tid;
  }
  __syncthreads();
  unsigned T16 = (unsigned)s_aux[0];
  int b = ch4 >> 1, ch = ch4 & 1;
  const float* row = att + ((size_t)b * 3 + 1 + ch) * SEQL;
  int per = (SEQL + TKB - 1) / TKB;
  int lo = blk * per;
  int hi = lo + per; if (hi > SEQL) hi = SEQL;
  for (int i = lo + tid; i < hi; i += 256) {
    unsigned key = __float_as_uint(row[i]);
    if ((key >> 16) >= T16) {
      int p = atomicAdd(&cnt[ch4], 1);
      if (p < CDCAP)
        cand[(size_t)ch4 * CDCAP + p] =
            ((unsigned long long)key << 32) | (unsigned)(~(unsigned)i);
    }
  }
}

// ---------------- K2: per batch — desc sort both channels, merge, asc sort --
__global__ __launch_bounds__(1024) void topk_final_kernel(
    const unsigned long long* __restrict__ cand, const int* __restrict__ cnt,
    int* __restrict__ idx) {
  __shared__ unsigned long long sc[CDCAP];
  __shared__ int m[512];
  int b = blockIdx.x, t = threadIdx.x;
  for (int ch = 0; ch < 2; ++ch) {
    int ch4 = b * 2 + ch;
    int n = cnt[ch4]; if (n > CDCAP) n = CDCAP;   // >=256 by construction
    int P = 256;
    while (P < n) P <<= 1;                        // typical 512
    for (int i = t; i < P; i += 1024)
      sc[i] = (i < n) ? cand[(size_t)ch4 * CDCAP + i] : 0ull;  // 0 sorts last
    __syncthreads();
    for (int k = 2; k <= P; k <<= 1) {
      for (int j = k >> 1; j > 0; j >>= 1) {
        for (int i = t; i < P; i += 1024) {
          int ixj = i ^ j;
          if (ixj > i) {
            unsigned long long va = sc[i], vb2 = sc[ixj];
            bool up = ((i & k) == 0);
            if ((va < vb2) == up) { sc[i] = vb2; sc[ixj] = va; }
          }
        }
        __syncthreads();
      }
    }
    if (t < 256)
      m[ch * 256 + t] = (int)~(unsigned)(sc[t] & 0xFFFFFFFFull);
    __syncthreads();
  }
  for (int k = 2; k <= 512; k <<= 1) {
    for (int j = k >> 1; j > 0; j >>= 1) {
      if (t < 512) {
        int ixj = t ^ j;
        if (ixj > t) {
          int va = m[t], vb2 = m[ixj];
          bool up = ((t & k) == 0);
          if ((va > vb2) == up) { m[t] = vb2; m[ixj] = va; }
        }
      }
      __syncthreads();
    }
  }
  if (t < 512) idx[b * 512 + t] = m[t];
}

// ---------------- K3: fused gather + LN1 + QKV layer 0 ----------------------
// kbT/vT layout (bf16): [((b*4+h)*4+dpack)*4096 + i*8 + (d&7)]
__global__ __launch_bounds__(128) void gqkv0_kernel(
    const float* __restrict__ x, const int* __restrict__ idx,
    const float* __restrict__ ln_g, const float* __restrict__ ln_b,
    const float* __restrict__ Wq, const float* __restrict__ Wk,
    const float* __restrict__ Wv, const float* __restrict__ Wrel,
    const float* __restrict__ rcb, const float* __restrict__ rpb,
    float* __restrict__ emb, float* __restrict__ qc,
    unsigned short* __restrict__ kbT, unsigned short* __restrict__ vT,
    float* __restrict__ wb) {
  __shared__ float qs[128];
  const int l = 0;
  int hd = threadIdx.x;        // 0..127
  int hh = hd >> 5, d = hd & 31;
  int row = blockIdx.x;        // b*512 + i
  int b = row >> 9, ii = row & 511;
  int li = idx[b * NSEL + ii];
  float h[32];
  float mu = 0.f;
  #pragma unroll
  for (int c = 0; c < 32; ++c) {
    h[c] = x[((size_t)b * CCH + c) * SEQL + li];
    mu += h[c];
  }
  if (hd < 32) emb[(size_t)row * CCH + hd] = h[hd];
  mu *= (1.0f / 32.0f);
  float var = 0.f;
  #pragma unroll
  for (int c = 0; c < 32; ++c) { float dd0 = h[c] - mu; var += dd0 * dd0; }
  var *= (1.0f / 32.0f);
  float rstd = rsqrtf(var + 1e-5f);
  const float* g = ln_g + l * CCH;
  const float* bb = ln_b + l * CCH;
  #pragma unroll
  for (int c = 0; c < 32; ++c) h[c] = (h[c] - mu) * rstd * g[c] + bb[c];
  const float* wq = Wq + (size_t)l * CCH * HDD + hd;
  const float* wk = Wk + (size_t)l * CCH * HDD + hd;
  const float* wv = Wv + (size_t)l * CCH * HDD + hd;
  float q = 0.f, kk = 0.f, vv = 0.f;
  #pragma unroll
  for (int c = 0; c < 32; ++c) {
    q += h[c] * wq[c * HDD];
    kk += h[c] * wk[c * HDD];
    vv += h[c] * wv[c * HDD];
  }
  q *= 0.17677669529663687f;   // DK^-0.5
  qs[hd] = q;
  qc[(size_t)row * HDD + hd] = q + rcb[(l * NHEAD + hh) * DKD + d];
  size_t tpos = ((size_t)(b * 4 + hh) * 4 + (d >> 3)) * 4096 + (size_t)ii * 8 + (d & 7);
  kbT[tpos] = f2bf(kk);
  vT[tpos]  = f2bf(vv);
  __syncthreads();
  if (hd < 120) {
    int h2 = hd / 30, f = hd % 30;
    const float* wr = Wrel + ((size_t)l * 30 + f) * HDD + h2 * DKD;
    const float* rp = rpb + (l * NHEAD + h2) * DKD;
    const float* qsh = qs + h2 * DKD;
    float acc = 0.f;
    #pragma unroll
    for (int dd = 0; dd < 32; ++dd) acc += (qsh[dd] + rp[dd]) * wr[dd];
    wb[((size_t)row * NHEAD + h2) * 32 + f] = acc;   // padded stride 32
  }
}

// ---------------- K4: attention (content + rel + softmax + PV) --------------
// 1024 blocks (b, h, 4 i-rows), 4 waves, 1 row/wave. E gathers: ONE uint4
// per pair (u8 features, 1/255 folded into w0/w1). PV reduction: stages
// {1,2,4} on 8 accs, select, stages {8,16,32} on one value (27 DS ops/dp
// instead of 48).
__global__ __launch_bounds__(256, 4) void attn_kernel(
    const float* __restrict__ qc, const unsigned short* __restrict__ kbT,
    const unsigned short* __restrict__ vT, const float* __restrict__ wbuf,
    const unsigned char* __restrict__ E, const int* __restrict__ idx,
    float* __restrict__ ob) {
  __shared__ int idxl[512];
  int bid = blockIdx.x;
  int b = bid >> 9;
  int h = (bid >> 7) & 3;
  int i0 = (bid & 127) * 4;
  int tid = threadIdx.x;
  int wv = tid >> 6, ln = tid & 63;
  for (int i = tid; i < 512; i += 256) idxl[i] = idx[b * NSEL + i];
  __syncthreads();
  int i = i0 + wv;
  const float* qrow = qc + (size_t)(b * NSEL + i) * HDD + h * DKD;
  float q[32];
  #pragma unroll
  for (int d4 = 0; d4 < 8; ++d4) {
    float4 qv = *(const float4*)(qrow + d4 * 4);
    q[d4 * 4 + 0] = qv.x; q[d4 * 4 + 1] = qv.y;
    q[d4 * 4 + 2] = qv.z; q[d4 * 4 + 3] = qv.w;
  }
  const float* wrow = wbuf + ((size_t)(b * NSEL + i) * NHEAD + h) * 32;
  float w0[15], w1[15];
  #pragma unroll
  for (int f = 0; f < 15; ++f) {
    w0[f] = wrow[f] * (1.0f / 255.0f);        // u8 scale folded in
    w1[f] = wrow[15 + f] * (1.0f / 255.0f);
  }
  int ii = idxl[i];
  const uint4* kb4 = (const uint4*)kbT + (size_t)(b * 4 + h) * 4 * 512;
  const uint4* vb4 = (const uint4*)vT + (size_t)(b * 4 + h) * 4 * 512;
  float lg[8];
  #pragma unroll
  for (int u = 0; u < 8; ++u) {
    int j = u * 64 + ln;
    int dj = ii - idxl[j];
    float cacc = 0.f;
    #pragma unroll
    for (int dp = 0; dp < 4; ++dp) {
      uint4 kv = kb4[dp * 512 + j];
      cacc += q[dp * 8 + 0] * BFL(kv.x) + q[dp * 8 + 1] * BFH(kv.x)
            + q[dp * 8 + 2] * BFL(kv.y) + q[dp * 8 + 3] * BFH(kv.y)
            + q[dp * 8 + 4] * BFL(kv.z) + q[dp * 8 + 5] * BFH(kv.z)
            + q[dp * 8 + 6] * BFL(kv.w) + q[dp * 8 + 7] * BFH(kv.w);
    }
    int a = dj < 0 ? -dj : dj;
    uint4 e = *(const uint4*)(E + (size_t)a * 16);    // one 16B gather
    float r0 = U8F(e.x, 0)  * w0[0]  + U8F(e.x, 8)  * w0[1]
             + U8F(e.x, 16) * w0[2]  + U8F(e.x, 24) * w0[3]
             + U8F(e.y, 0)  * w0[4]  + U8F(e.y, 8)  * w0[5]
             + U8F(e.y, 16) * w0[6]  + U8F(e.y, 24) * w0[7]
             + U8F(e.z, 0)  * w0[8]  + U8F(e.z, 8)  * w0[9]
             + U8F(e.z, 16) * w0[10] + U8F(e.z, 24) * w0[11]
             + U8F(e.w, 0)  * w0[12] + U8F(e.w, 8)  * w0[13]
             + U8F(e.w, 16) * w0[14];
    float r1 = U8F(e.x, 0)  * w1[0]  + U8F(e.x, 8)  * w1[1]
             + U8F(e.x, 16) * w1[2]  + U8F(e.x, 24) * w1[3]
             + U8F(e.y, 0)  * w1[4]  + U8F(e.y, 8)  * w1[5]
             + U8F(e.y, 16) * w1[6]  + U8F(e.y, 24) * w1[7]
             + U8F(e.z, 0)  * w1[8]  + U8F(e.z, 8)  * w1[9]
             + U8F(e.z, 16) * w1[10] + U8F(e.z, 24) * w1[11]
             + U8F(e.w, 0)  * w1[12] + U8F(e.w, 8)  * w1[13]
             + U8F(e.w, 16) * w1[14];
    float sgn = dj > 0 ? 1.f : (dj < 0 ? -1.f : 0.f);
    lg[u] = cacc + r0 + sgn * r1;
  }
  // full-row softmax across the wave (512 logits, 8/lane), in registers
  float m = lg[0];
  #pragma unroll
  for (int u = 1; u < 8; ++u) m = fmaxf(m, lg[u]);
  #pragma unroll
  for (int s = 1; s < 64; s <<= 1) m = fmaxf(m, __shfl_xor(m, s));
  float ssum = 0.f;
  #pragma unroll
  for (int u = 0; u < 8; ++u) { lg[u] = __expf(lg[u] - m); ssum += lg[u]; }
  #pragma unroll
  for (int s = 1; s < 64; s <<= 1) ssum += __shfl_xor(ssum, s);
  float invs = 1.0f / ssum;
  // PV: p in registers, v coalesced; reduced-shuffle epilogue
  float* obrow = ob + (size_t)(b * NSEL + i) * HDD + h * DKD;
  #pragma unroll
  for (int dp = 0; dp < 4; ++dp) {
    float acc[8] = {0.f, 0.f, 0.f, 0.f, 0.f, 0.f, 0.f, 0.f};
    #pragma unroll
    for (int u = 0; u < 8; ++u) {
      uint4 vv = vb4[dp * 512 + u * 64 + ln];
      float p = lg[u];
      acc[0] += p * BFL(vv.x); acc[1] += p * BFH(vv.x);
      acc[2] += p * BFL(vv.y); acc[3] += p * BFH(vv.y);
      acc[4] += p * BFL(vv.z); acc[5] += p * BFH(vv.z);
      acc[6] += p * BFL(vv.w); acc[7] += p * BFH(vv.w);
    }
    // octet-reduce all 8 accs (stages 1,2,4)
    #pragma unroll
    for (int s = 1; s < 8; s <<= 1) {
      #pragma unroll
      for (int t = 0; t < 8; ++t) acc[t] += __shfl_xor(acc[t], s);
    }
    // lane picks its d = ln&7, then cross-octet reduce (stages 8,16,32)
    int sel = ln & 7;
    float y = acc[0];
    #pragma unroll
    for (int t = 1; t < 8; ++t) y = (sel == t) ? acc[t] : y;
    #pragma unroll
    for (int s = 8; s < 64; s <<= 1) y += __shfl_xor(y, s);
    if (ln < 8) obrow[dp * 8 + ln] = y * invs;
  }
}

// ---------------- K5: fused proj+res+LN2+MLP+res (2 rows) + qkv(l+1)/scatter
__global__ __launch_bounds__(256) void mlpqkv_kernel(
    const float* __restrict__ ob, const float* __restrict__ Wo,
    const float* __restrict__ bo,
    const float* __restrict__ ln2_g, const float* __restrict__ ln2_b,
    const float* __restrict__ W1, const float* __restrict__ b1,
    const float* __restrict__ W2, const float* __restrict__ b2,
    const float* __restrict__ ln1_g, const float* __restrict__ ln1_b,
    const float* __restrict__ Wq, const float* __restrict__ Wk,
    const float* __restrict__ Wv, const float* __restrict__ Wrel,
    const float* __restrict__ rcb, const float* __restrict__ rpb,
    const int* __restrict__ idx, float* __restrict__ emb,
    float* __restrict__ qc, unsigned short* __restrict__ kbT,
    unsigned short* __restrict__ vT, float* __restrict__ wb,
    float* __restrict__ out, int layer) {
  __shared__ float part[2][8][32];
  __shared__ float res[2][32];
  __shared__ float hln[2][32];
  __shared__ float fin[2][32];
  __shared__ float a1s[2][MLPD];
  __shared__ float qs[2][128];
  int row0 = blockIdx.x * 2;
  int tid = threadIdx.x;
  int c = tid & 31, seg = tid >> 5;
  const float* wo = Wo + (size_t)layer * HDD * CCH + c;
  float pacc[2] = {0.f, 0.f};
  #pragma unroll
  for (int k = 0; k < 16; ++k) {
    int kk = seg * 16 + k;
    float w = wo[kk * CCH];
    #pragma unroll
    for (int r = 0; r < 2; ++r)
      pacc[r] += ob[(size_t)(row0 + r) * HDD + kk] * w;
  }
  #pragma unroll
  for (int r = 0; r < 2; ++r) part[r][seg][c] = pacc[r];
  __syncthreads();
  if (tid < 64) {
    int r = tid >> 5, cc = tid & 31;
    float s = bo[layer * CCH + cc] + emb[(size_t)(row0 + r) * CCH + cc];
    #pragma unroll
    for (int sg = 0; sg < 8; ++sg) s += part[r][sg][cc];
    res[r][cc] = s;
  }
  __syncthreads();
  if (tid < 64) {
    int r = tid >> 5, cc = tid & 31;
    float mu = 0.f, s2 = 0.f;
    #pragma unroll
    for (int c2 = 0; c2 < 32; ++c2) { float v = res[r][c2]; mu += v; s2 += v * v; }
    mu *= (1.0f / 32.0f);
    float var = s2 * (1.0f / 32.0f) - mu * mu;
    float rstd = rsqrtf(var + 1e-5f);
    hln[r][cc] = (res[r][cc] - mu) * rstd * ln2_g[layer * CCH + cc] + ln2_b[layer * CCH + cc];
  }
  __syncthreads();
  const float* w1 = W1 + (size_t)layer * CCH * MLPD;
  float accA[2], accB[2];
  float bA = b1[layer * MLPD + tid], bB = b1[layer * MLPD + tid + 256];
  #pragma unroll
  for (int r = 0; r < 2; ++r) { accA[r] = bA; accB[r] = bB; }
  for (int c2 = 0; c2 < 32; ++c2) {
    float wa = w1[c2 * MLPD + tid];
    float wb2 = w1[c2 * MLPD + tid + 256];
    #pragma unroll
    for (int r = 0; r < 2; ++r) {
      float hv = hln[r][c2];
      accA[r] += hv * wa;
      accB[r] += hv * wb2;
    }
  }
  #pragma unroll
  for (int r = 0; r < 2; ++r) {
    a1s[r][tid]       = 0.5f * accA[r] * (1.0f + erff(accA[r] * 0.70710678118654752f));
    a1s[r][tid + 256] = 0.5f * accB[r] * (1.0f + erff(accB[r] * 0.70710678118654752f));
  }
  __syncthreads();
  const float* w2 = W2 + (size_t)layer * MLPD * CCH;
  float acc2[2] = {0.f, 0.f};
  #pragma unroll 4
  for (int mi = 0; mi < 64; ++mi) {
    int m = seg * 64 + mi;
    float w = w2[m * CCH + c];
    #pragma unroll
    for (int r = 0; r < 2; ++r) acc2[r] += a1s[r][m] * w;
  }
  __syncthreads();                    // part[] reuse
  #pragma unroll
  for (int r = 0; r < 2; ++r) part[r][seg][c] = acc2[r];
  __syncthreads();
  if (tid < 64) {
    int r = tid >> 5, cc = tid & 31;
    float s = b2[layer * CCH + cc] + res[r][cc];
    #pragma unroll
    for (int sg = 0; sg < 8; ++sg) s += part[r][sg][cc];
    fin[r][cc] = s;
    if (layer < 3) emb[(size_t)(row0 + r) * CCH + cc] = s;
  }
  __syncthreads();
  if (layer == 3) {
    if (tid < 64) {
      int r = tid >> 5, cc = tid & 31;
      int row = row0 + r;
      int b = row >> 9, ii = row & 511;
      int li = idx[b * NSEL + ii];
      out[((size_t)b * CCH + cc) * SEQL + li] = fin[r][cc];
    }
    return;
  }
  const int l1 = layer + 1;
  bool act = tid < 128;
  int hd = tid & 127;
  int hh = hd >> 5, d = hd & 31;
  #pragma unroll
  for (int r = 0; r < 2; ++r) {
    int row = row0 + r;
    int b = row >> 9, ii = row & 511;
    if (act) {
      float h[32];
      float mu = 0.f;
      #pragma unroll
      for (int c2 = 0; c2 < 32; ++c2) { h[c2] = fin[r][c2]; mu += h[c2]; }
      mu *= (1.0f / 32.0f);
      float var = 0.f;
      #pragma unroll
      for (int c2 = 0; c2 < 32; ++c2) { float dd = h[c2] - mu; var += dd * dd; }
      var *= (1.0f / 32.0f);
      float rstd = rsqrtf(var + 1e-5f);
      const float* g = ln1_g + l1 * CCH;
      const float* bb = ln1_b + l1 * CCH;
      #pragma unroll
      for (int c2 = 0; c2 < 32; ++c2) h[c2] = (h[c2] - mu) * rstd * g[c2] + bb[c2];
      const float* wq = Wq + (size_t)l1 * CCH * HDD + hd;
      const float* wk = Wk + (size_t)l1 * CCH * HDD + hd;
      const float* wv = Wv + (size_t)l1 * CCH * HDD + hd;
      float q = 0.f, kk = 0.f, vv = 0.f;
      #pragma unroll
      for (int c2 = 0; c2 < 32; ++c2) {
        q += h[c2] * wq[c2 * HDD];
        kk += h[c2] * wk[c2 * HDD];
        vv += h[c2] * wv[c2 * HDD];
      }
      q *= 0.17677669529663687f;
      qs[r][hd] = q;
      qc[(size_t)row * HDD + hd] = q + rcb[(l1 * NHEAD + hh) * DKD + d];
      size_t tpos = ((size_t)(b * 4 + hh) * 4 + (d >> 3)) * 4096 + (size_t)ii * 8 + (d & 7);
      kbT[tpos] = f2bf(kk);
      vT[tpos]  = f2bf(vv);
    }
  }
  __syncthreads();
  if (act && hd < 120) {
    int h2 = hd / 30, f = hd % 30;
    const float* rp = rpb + (l1 * NHEAD + h2) * DKD;
    const float* wr = Wrel + ((size_t)l1 * 30 + f) * HDD + h2 * DKD;
    #pragma unroll
    for (int r = 0; r < 2; ++r) {
      int row = row0 + r;
      const float* qsh = qs[r] + h2 * DKD;
      float acc = 0.f;
      #pragma unroll
      for (int dd = 0; dd < 32; ++dd) acc += (qsh[dd] + rp[dd]) * wr[dd];
      wb[((size_t)row * NHEAD + h2) * 32 + f] = acc;
    }
  }
}

extern "C" void kernel_launch(void* const* d_in, const int* in_sizes, int n_in,
                              void* d_out, int out_size, void* d_ws, size_t ws_size,
                              hipStream_t stream) {
  (void)in_sizes; (void)n_in; (void)ws_size; (void)out_size;
  const float* x_skip    = (const float*)d_in[0];
  const float* attention = (const float*)d_in[1];
  const float* ln1_g = (const float*)d_in[2];
  const float* ln1_b = (const float*)d_in[3];
  const float* Wq    = (const float*)d_in[4];
  const float* Wk    = (const float*)d_in[5];
  const float* Wv    = (const float*)d_in[6];
  const float* Wrel  = (const float*)d_in[7];
  const float* rcb   = (const float*)d_in[8];
  const float* rpb   = (const float*)d_in[9];
  const float* Wo    = (const float*)d_in[10];
  const float* bo    = (const float*)d_in[11];
  const float* ln2_g = (const float*)d_in[12];
  const float* ln2_b = (const float*)d_in[13];
  const float* W1    = (const float*)d_in[14];
  const float* b1    = (const float*)d_in[15];
  const float* W2    = (const float*)d_in[16];
  const float* b2    = (const float*)d_in[17];
  float* out = (float*)d_out;
  char* ws = (char*)d_ws;

  unsigned char* E = (unsigned char*)(ws + 0);        // 45000*16 = 720,000
  int*      idx   = (int*)(ws + 1441792);             // 4,096
  float*    emb   = (float*)(ws + 1445888);           // 131,072
  float*    qc    = (float*)(ws + 1576960);           // 524,288
  unsigned short* kbT = (unsigned short*)(ws + 2101248); // 262,144
  unsigned short* vT  = (unsigned short*)(ws + 2363392); // 262,144
  float*    wb    = (float*)(ws + 2625536);           // 524,288
  float*    ob    = (float*)(ws + 3149824);           // 524,288
  int*      hist  = (int*)(ws + 3674112);             // 1,048,576
  int*      cnt   = (int*)(ws + 4722688);             // 16
  unsigned long long* cand = (unsigned long long*)(ws + 4722720); // 65,536

  hipMemsetAsync(ws + 3674112, 0, 1048576 + 32, stream);   // hist + cnt
  prep_kernel<<<ETB + 4 * TKB, 256, 0, stream>>>(attention, E, hist, out);
  topk_collect_kernel<<<4 * TKB, 256, 0, stream>>>(attention, hist, cand, cnt);
  topk_final_kernel<<<2, 1024, 0, stream>>>(cand, cnt, idx);
  gqkv0_kernel<<<1024, 128, 0, stream>>>(x_skip, idx, ln1_g, ln1_b, Wq, Wk, Wv,
                                         Wrel, rcb, rpb, emb, qc, kbT, vT, wb);
  for (int l = 0; l < 4; ++l) {
    attn_kernel<<<1024, 256, 0, stream>>>(qc, kbT, vT, wb, E, idx, ob);
    mlpqkv_kernel<<<512, 256, 0, stream>>>(ob, Wo, bo, ln2_g, ln2_b, W1, b1,
                                           W2, b2, ln1_g, ln1_b, Wq, Wk, Wv,
                                           Wrel, rcb, rpb, idx, emb, qc, kbT,
                                           vT, wb, out, l);
  }
}